// Round 14
// baseline (367.127 us; speedup 1.0000x reference)
//
#include <hip/hip_runtime.h>
#include <math.h>

#define H 2048
#define E 64
#define TAU 1e-6f     // p-gap guard (proven r3/5-r13): logit err ~2.5e-7 -> p err ~4e-9 << TAU

// ---- MFMA path geometry ----
#define MT 64         // rows per block -> grid 256 = 1 block/CU, 8 waves

// ---- round-5 fallback geometry ----
#define RB 16
#define CB 512
#define NCH (H / CB)
#define PITCH 516

// d_ws layout
#define WHI_OFF 65792u                     // after flags (65540 B), 256-aligned
#define WFRAG_BYTES 262144u                // 64kc * 4n * 64lane * 8 bf16 * 2B
#define WLO_OFF (WHI_OFF + WFRAG_BYTES)
#define WS_NEEDED ((size_t)(WLO_OFF + WFRAG_BYTES))   // 590080

// ---- ablation (diagnostic) ----
#define ABL_REP 6
#define ABL_SCRATCH_OFF (4u * 1024u * 1024u)   // junk region in d_ws (never validated)

typedef __attribute__((ext_vector_type(8))) short short8;
typedef __attribute__((ext_vector_type(4))) float f32x4;

__device__ __forceinline__ unsigned short bf16_rne(float f) {
    unsigned u = __float_as_uint(f);
    unsigned r = u + 0x7fffu + ((u >> 16) & 1u);
    return (unsigned short)(r >> 16);
}

// ============ kernel P: W' = pds*W (f64), split into bf16 hi/lo B-fragments ============
__global__ __launch_bounds__(64)
void prep_w(const float* __restrict__ Wm, const float* __restrict__ pds,
            int* __restrict__ flags,
            unsigned short* __restrict__ whi, unsigned short* __restrict__ wlo)
{
    const int fb   = blockIdx.x;        // 0..255 = kc*4 + n
    const int lane = threadIdx.x;       // 0..63
    if (fb == 0 && lane == 0) flags[0] = 0;
    const int kc  = fb >> 2;
    const int n   = fb & 3;
    const int r0  = kc * 32 + (lane >> 4) * 8;
    const int col = n * 16 + (lane & 15);

    short8 hv, lv;
#pragma unroll
    for (int j = 0; j < 8; ++j) {
        const int r = r0 + j;
        const double w = (double)pds[r] * (double)Wm[r * E + col];  // exact in f64
        const unsigned short hb = bf16_rne((float)w);
        const double hd = (double)__uint_as_float((unsigned)hb << 16);
        const unsigned short lb = bf16_rne((float)(w - hd));
        hv[j] = (short)hb;
        lv[j] = (short)lb;
    }
    const size_t off = ((size_t)fb * 64 + lane) * 8;
    *(short8*)(whi + off) = hv;
    *(short8*)(wlo + off) = lv;
}

// ============ kernel M: 4-tile W-amortized MFMA router (r13, verified) ============
__global__ __launch_bounds__(512, 2)
void router_4t(const float* __restrict__ x,
               const unsigned short* __restrict__ whi,
               const unsigned short* __restrict__ wlo,
               float* __restrict__ out,
               int* __restrict__ flags)
{
    __shared__ float lbuf[4][MT * E];   // partial logits (two-stage merge), 64 KB
    __shared__ float ssbuf[8][MT];      // per-wave sum(x^2) partials
    __shared__ float sfac[MT];

    const int t    = threadIdx.x;
    const int wid  = t >> 6;            // 0..7, owns kc in [wid*8, wid*8+8)
    const int lane = t & 63;
    const int lsub = lane & 15;         // A-frag row-in-tile
    const int lgrp = lane >> 4;         // A-frag k-group
    const int row0 = blockIdx.x * MT;

    f32x4 acc[4][4];
#pragma unroll
    for (int a = 0; a < 4; ++a)
#pragma unroll
        for (int b = 0; b < 4; ++b) acc[a][b] = (f32x4){0.f, 0.f, 0.f, 0.f};
    float sq[4] = {0.f, 0.f, 0.f, 0.f};

    const float* xw = x + (size_t)row0 * H + wid * 256 + lgrp * 8;

    for (int kl = 0; kl < 8; ++kl) {
        const int kc = wid * 8 + kl;

        const unsigned short* ph = whi + ((size_t)kc * 256 + lane) * 8;
        const unsigned short* pl = wlo + ((size_t)kc * 256 + lane) * 8;
        short8 WH[4], WL[4];
#pragma unroll
        for (int n = 0; n < 4; ++n) {
            WH[n] = *(const short8*)(ph + n * 512);
            WL[n] = *(const short8*)(pl + n * 512);
        }

        float4 a0[4], a1[4];
#pragma unroll
        for (int tt = 0; tt < 4; ++tt) {
            const float* p = xw + (size_t)(tt * 16 + lsub) * H + kl * 32;
            a0[tt] = *(const float4*)p;
            a1[tt] = *(const float4*)(p + 4);
        }

        short8 AH[4], AL[4];
#pragma unroll
        for (int tt = 0; tt < 4; ++tt) {
            const float f[8] = { a0[tt].x, a0[tt].y, a0[tt].z, a0[tt].w,
                                 a1[tt].x, a1[tt].y, a1[tt].z, a1[tt].w };
            sq[tt] += f[0]*f[0] + f[1]*f[1] + f[2]*f[2] + f[3]*f[3]
                    + f[4]*f[4] + f[5]*f[5] + f[6]*f[6] + f[7]*f[7];
#pragma unroll
            for (int e = 0; e < 8; ++e) {
                const unsigned short hb = bf16_rne(f[e]);
                const unsigned short lb = bf16_rne(f[e] - __uint_as_float((unsigned)hb << 16));
                AH[tt][e] = (short)hb;
                AL[tt][e] = (short)lb;
            }
        }

#pragma unroll
        for (int tt = 0; tt < 4; ++tt)
#pragma unroll
            for (int n = 0; n < 4; ++n) {
                acc[tt][n] = __builtin_amdgcn_mfma_f32_16x16x32_bf16(AH[tt], WH[n], acc[tt][n], 0, 0, 0);
                acc[tt][n] = __builtin_amdgcn_mfma_f32_16x16x32_bf16(AH[tt], WL[n], acc[tt][n], 0, 0, 0);
                acc[tt][n] = __builtin_amdgcn_mfma_f32_16x16x32_bf16(AL[tt], WH[n], acc[tt][n], 0, 0, 0);
            }
    }

#pragma unroll
    for (int tt = 0; tt < 4; ++tt) {
        float s = sq[tt];
        s += __shfl_xor(s, 16);
        s += __shfl_xor(s, 32);
        if (lane < 16) ssbuf[wid][tt * 16 + lane] = s;
    }

    if (wid < 4) {
#pragma unroll
        for (int tt = 0; tt < 4; ++tt)
#pragma unroll
            for (int n = 0; n < 4; ++n)
#pragma unroll
                for (int q = 0; q < 4; ++q)
                    lbuf[wid][(tt * 16 + lgrp * 4 + q) * E + n * 16 + lsub] = acc[tt][n][q];
    }
    __syncthreads();
    if (wid >= 4) {
#pragma unroll
        for (int tt = 0; tt < 4; ++tt)
#pragma unroll
            for (int n = 0; n < 4; ++n)
#pragma unroll
                for (int q = 0; q < 4; ++q)
                    lbuf[wid - 4][(tt * 16 + lgrp * 4 + q) * E + n * 16 + lsub] += acc[tt][n][q];
    }
    __syncthreads();

    if (t < MT) {
        const float tot = ssbuf[0][t] + ssbuf[1][t] + ssbuf[2][t] + ssbuf[3][t]
                        + ssbuf[4][t] + ssbuf[5][t] + ssbuf[6][t] + ssbuf[7][t];
        sfac[t] = rsqrtf(tot * (1.0f / (float)H) + 1e-6f) * 0.022097086912079608f;
    }
    __syncthreads();

#pragma unroll
    for (int rr = 0; rr < 8; ++rr) {
        const int r = wid * 8 + rr;
        const float L = (lbuf[0][r * E + lane] + lbuf[1][r * E + lane]
                       + lbuf[2][r * E + lane] + lbuf[3][r * E + lane]) * sfac[r];

        float m = L;
#pragma unroll
        for (int off = 32; off >= 1; off >>= 1)
            m = fmaxf(m, __shfl_xor(m, off));
        const float ev = expf(L - m);
        float S = ev;
#pragma unroll
        for (int off = 32; off >= 1; off >>= 1)
            S += __shfl_xor(S, off);
        const float p = ev / S;

        float v1 = p; int i1 = lane;
#pragma unroll
        for (int off = 32; off >= 1; off >>= 1) {
            const float ov = __shfl_xor(v1, off);
            const int   oi = __shfl_xor(i1, off);
            if (ov > v1 || (ov == v1 && oi < i1)) { v1 = ov; i1 = oi; }
        }
        float v2 = (lane == i1) ? -1.0f : p; int i2 = lane;
#pragma unroll
        for (int off = 32; off >= 1; off >>= 1) {
            const float ov = __shfl_xor(v2, off);
            const int   oi = __shfl_xor(i2, off);
            if (ov > v2 || (ov == v2 && oi < i2)) { v2 = ov; i2 = oi; }
        }
        float v3 = (lane == i1 || lane == i2) ? -1.0f : p;
#pragma unroll
        for (int off = 32; off >= 1; off >>= 1)
            v3 = fmaxf(v3, __shfl_xor(v3, off));

        if (lane == 0 && (v2 - v3) < TAU) {
            const int k = atomicAdd(flags, 1);
            flags[1 + k] = row0 + r;
        }

        const float denom = fmaxf(v1 + v2, 1e-9f);
        const float wA = v1 / denom;
        const float wB = v2 / denom;
        const float o  = (lane == i1) ? wA : ((lane == i2) ? wB : 0.0f);
        out[(size_t)(row0 + r) * E + lane] = o;
    }
}

// ============ kernel F: exact-f64 repair of flagged rows (round-3 proven) ============
__global__ __launch_bounds__(256)
void router_fix(const float* __restrict__ x,
                const float* __restrict__ pds,
                const float* __restrict__ Wm,
                float* __restrict__ out,
                const int* __restrict__ flags)
{
    __shared__ double yd[H];
    __shared__ double parts[4 * E];
    __shared__ double ss[256];

    const int t = threadIdx.x;
    const int count = flags[0];

    for (int j = blockIdx.x; j < count; j += gridDim.x) {
        const int r = flags[1 + j];
        const float* xr = x + (size_t)r * H;

        double s = 0.0;
#pragma unroll
        for (int i = 0; i < 8; ++i) {
            const int h = t * 8 + i;
            const double xv = (double)xr[h];
            s += xv * xv;
            yd[h] = xv * (double)pds[h];
        }
        ss[t] = s;
        __syncthreads();

        const int ex = t & 63;
        const int sl = t >> 6;
        const float* wp = Wm + (size_t)(sl * 512) * E + ex;
        double acc = 0.0;
#pragma unroll 8
        for (int h = 0; h < 512; ++h)
            acc = fma(yd[sl * 512 + h], (double)wp[(size_t)h * E], acc);
        parts[sl * E + ex] = acc;
        __syncthreads();

        if (t < 64) {
            const int lane = t;
            double tot = ss[lane * 4] + ss[lane * 4 + 1] + ss[lane * 4 + 2] + ss[lane * 4 + 3];
#pragma unroll
            for (int off = 32; off >= 1; off >>= 1)
                tot += __shfl_xor(tot, off);
            const double sf = (1.0 / sqrt(tot * (1.0 / (double)H) + 1e-6)) * 0.022097086912079608;

            const double Ld = parts[0 * E + lane] + parts[1 * E + lane]
                            + parts[2 * E + lane] + parts[3 * E + lane];
            const float L = (float)(Ld * sf);

            float m = L;
#pragma unroll
            for (int off = 32; off >= 1; off >>= 1)
                m = fmaxf(m, __shfl_xor(m, off));
            const float ev = (float)exp((double)(L - m));
            float S = ev;
#pragma unroll
            for (int off = 32; off >= 1; off >>= 1)
                S += __shfl_xor(S, off);
            const float p = ev / S;

            float v1 = p; int i1 = lane;
#pragma unroll
            for (int off = 32; off >= 1; off >>= 1) {
                const float ov = __shfl_xor(v1, off);
                const int   oi = __shfl_xor(i1, off);
                if (ov > v1 || (ov == v1 && oi < i1)) { v1 = ov; i1 = oi; }
            }
            float v2 = (lane == i1) ? -1.0f : p; int i2 = lane;
#pragma unroll
            for (int off = 32; off >= 1; off >>= 1) {
                const float ov = __shfl_xor(v2, off);
                const int   oi = __shfl_xor(i2, off);
                if (ov > v2 || (ov == v2 && oi < i2)) { v2 = ov; i2 = oi; }
            }

            const float denom = fmaxf(v1 + v2, 1e-9f);
            const float wA = v1 / denom;
            const float wB = v2 / denom;
            const float o  = (lane == i1) ? wA : ((lane == i2) ? wB : 0.0f);
            out[(size_t)r * E + lane] = o;
        }
        __syncthreads();
    }
}

// ============ ABLATION A: r13's exact x access pattern, loads only ============
// Row-tile-interleaved 128B segments (the invariant of r5-r13). 6 reps => >76us
// => forced into rocprof top-5 WITH counters. Sum kept live via real store.
__global__ __launch_bounds__(512)
void abl_x(const float* __restrict__ x, float* __restrict__ junk)
{
    const int t    = threadIdx.x;
    const int wid  = t >> 6;
    const int lane = t & 63;
    const int lsub = lane & 15;
    const int lgrp = lane >> 4;
    const int row0 = blockIdx.x * MT;

    float s = 0.0f;
    for (int rep = 0; rep < ABL_REP; ++rep) {
        int off = 0;
        asm volatile("" : "+v"(off));      // opaque zero: defeats rep-hoisting
        const float* xw = x + (size_t)row0 * H + wid * 256 + lgrp * 8 + off;
        for (int kl = 0; kl < 8; ++kl) {
#pragma unroll
            for (int tt = 0; tt < 4; ++tt) {
                const float* p = xw + (size_t)(tt * 16 + lsub) * H + kl * 32;
                const float4 a0 = *(const float4*)p;
                const float4 a1 = *(const float4*)(p + 4);
                s += a0.x + a0.y + a0.z + a0.w + a1.x + a1.y + a1.z + a1.w;
            }
        }
    }
    junk[(size_t)blockIdx.x * 512 + t] = s;
}

// ============ ABLATION B: same bytes, LINEAR per-block walk (fill-like) ============
__global__ __launch_bounds__(512)
void abl_lin(const float* __restrict__ x, float* __restrict__ junk)
{
    const int t = threadIdx.x;
    const size_t base = (size_t)blockIdx.x * (MT * H);   // block's contiguous 512KB span

    float s = 0.0f;
    for (int rep = 0; rep < ABL_REP; ++rep) {
        int off = 0;
        asm volatile("" : "+v"(off));
        const float* sp = x + base + off;
        for (int i = 0; i < 64; ++i) {
            const float4 v = *(const float4*)(sp + i * 2048 + t * 4);
            s += v.x + v.y + v.z + v.w;
        }
    }
    junk[131072 + (size_t)blockIdx.x * 512 + t] = s;
}

// ============ round-5 fallback (verified) in case ws_size is small ============
__global__ void zero_cnt(int* __restrict__ flags) {
    if (threadIdx.x == 0 && blockIdx.x == 0) flags[0] = 0;
}

__global__ __launch_bounds__(256)
void router_f32(const float* __restrict__ x,
                const float* __restrict__ pds,
                const float* __restrict__ Wm,
                float* __restrict__ out,
                int* __restrict__ flags)
{
    __shared__ __align__(16) float yb[RB * PITCH];
    __shared__ float ssbuf[256];
    __shared__ float sfac[RB];

    const int t    = threadIdx.x;
    const int wv_i = t >> 6;
    const int lane = t & 63;
    const int g    = lane >> 4;
    const int e0   = (lane & 15) << 2;

    const int row0 = blockIdx.x * RB;
    const int srow = t >> 4;
    const int sseg = t & 15;

    const float* xrow = x + (size_t)(row0 + srow) * H;

    float acc[4][4];
#pragma unroll
    for (int a = 0; a < 4; ++a)
#pragma unroll
        for (int b = 0; b < 4; ++b) acc[a][b] = 0.0f;

    float sumsq = 0.0f;
    float4 xv[8];
#pragma unroll
    for (int i = 0; i < 8; ++i)
        xv[i] = *(const float4*)(xrow + sseg * 4 + i * 64);

    for (int c = 0; c < NCH; ++c) {
        const float* pbase = pds + c * CB;
#pragma unroll
        for (int i = 0; i < 8; ++i) {
            const int hl = sseg * 4 + i * 64;
            const float4 a4 = xv[i];
            const float4 p4 = *(const float4*)(pbase + hl);
            sumsq += a4.x * a4.x + a4.y * a4.y + a4.z * a4.z + a4.w * a4.w;
            float4 y4;
            y4.x = a4.x * p4.x; y4.y = a4.y * p4.y;
            y4.z = a4.z * p4.z; y4.w = a4.w * p4.w;
            *(float4*)(&yb[srow * PITCH + hl]) = y4;
        }
        __syncthreads();

        if (c + 1 < NCH) {
            const int h0n = (c + 1) * CB;
#pragma unroll
            for (int i = 0; i < 8; ++i)
                xv[i] = *(const float4*)(xrow + h0n + sseg * 4 + i * 64);
        }

        const int hb = wv_i * 128;
        const float* wbase = Wm + (size_t)(c * CB) * E + e0;
#pragma unroll 2
        for (int s = 0; s < 32; ++s) {
            const int hh = hb + s * 4;
            const float4 w0 = *(const float4*)(wbase + (size_t)(hh + 0) * E);
            const float4 w1 = *(const float4*)(wbase + (size_t)(hh + 1) * E);
            const float4 w2 = *(const float4*)(wbase + (size_t)(hh + 2) * E);
            const float4 w3 = *(const float4*)(wbase + (size_t)(hh + 3) * E);
#pragma unroll
            for (int rr = 0; rr < 4; ++rr) {
                const float4 y4 = *(const float4*)(&yb[(4 * rr + g) * PITCH + hh]);
                acc[rr][0] = fmaf(y4.w, w3.x, fmaf(y4.z, w2.x, fmaf(y4.y, w1.x, fmaf(y4.x, w0.x, acc[rr][0]))));
                acc[rr][1] = fmaf(y4.w, w3.y, fmaf(y4.z, w2.y, fmaf(y4.y, w1.y, fmaf(y4.x, w0.y, acc[rr][1]))));
                acc[rr][2] = fmaf(y4.w, w3.z, fmaf(y4.z, w2.z, fmaf(y4.y, w1.z, fmaf(y4.x, w0.z, acc[rr][2]))));
                acc[rr][3] = fmaf(y4.w, w3.w, fmaf(y4.z, w2.w, fmaf(y4.y, w1.w, fmaf(y4.x, w0.w, acc[rr][3]))));
            }
        }
        __syncthreads();
    }

    ssbuf[t] = sumsq;
    __syncthreads();
    if (t < RB) {
        float tot = 0.0f;
#pragma unroll
        for (int i = 0; i < 16; ++i) tot += ssbuf[t * 16 + i];
        sfac[t] = rsqrtf(tot * (1.0f / (float)H) + 1e-6f) * 0.022097086912079608f;
    }

#pragma unroll
    for (int rr = 0; rr < 4; ++rr) {
        const int r = 4 * rr + g;
        *(float4*)(&yb[((wv_i * RB) + r) * E + e0]) =
            make_float4(acc[rr][0], acc[rr][1], acc[rr][2], acc[rr][3]);
    }
    __syncthreads();

#pragma unroll
    for (int rr = 0; rr < 4; ++rr) {
        const int r = wv_i * 4 + rr;
        float L = yb[(0 * RB + r) * E + lane] + yb[(1 * RB + r) * E + lane]
                + yb[(2 * RB + r) * E + lane] + yb[(3 * RB + r) * E + lane];
        L *= sfac[r];

        float m = L;
#pragma unroll
        for (int off = 32; off >= 1; off >>= 1)
            m = fmaxf(m, __shfl_xor(m, off));
        const float ev = expf(L - m);
        float S = ev;
#pragma unroll
        for (int off = 32; off >= 1; off >>= 1)
            S += __shfl_xor(S, off);
        const float p = ev / S;

        float v1 = p; int i1 = lane;
#pragma unroll
        for (int off = 32; off >= 1; off >>= 1) {
            const float ov = __shfl_xor(v1, off);
            const int   oi = __shfl_xor(i1, off);
            if (ov > v1 || (ov == v1 && oi < i1)) { v1 = ov; i1 = oi; }
        }
        float v2 = (lane == i1) ? -1.0f : p; int i2 = lane;
#pragma unroll
        for (int off = 32; off >= 1; off >>= 1) {
            const float ov = __shfl_xor(v2, off);
            const int   oi = __shfl_xor(i2, off);
            if (ov > v2 || (ov == v2 && oi < i2)) { v2 = ov; i2 = oi; }
        }
        float v3 = (lane == i1 || lane == i2) ? -1.0f : p;
#pragma unroll
        for (int off = 32; off >= 1; off >>= 1)
            v3 = fmaxf(v3, __shfl_xor(v3, off));

        if (lane == 0 && (v2 - v3) < TAU) {
            const int k = atomicAdd(flags, 1);
            flags[1 + k] = row0 + r;
        }

        const float denom = fmaxf(v1 + v2, 1e-9f);
        const float wA = v1 / denom;
        const float wB = v2 / denom;
        const float o  = (lane == i1) ? wA : ((lane == i2) ? wB : 0.0f);
        out[(size_t)(row0 + r) * E + lane] = o;
    }
}

extern "C" void kernel_launch(void* const* d_in, const int* in_sizes, int n_in,
                              void* d_out, int out_size, void* d_ws, size_t ws_size,
                              hipStream_t stream) {
    const float* x   = (const float*)d_in[0];
    const float* pds = (const float*)d_in[1];
    const float* Wm  = (const float*)d_in[2];
    float* out = (float*)d_out;
    int* flags = (int*)d_ws;

    const int T = in_sizes[0] / H;   // 16384

    if (ws_size >= WS_NEEDED) {
        unsigned short* whi = (unsigned short*)((char*)d_ws + WHI_OFF);
        unsigned short* wlo = (unsigned short*)((char*)d_ws + WLO_OFF);
        hipLaunchKernelGGL(prep_w,     dim3(256),    dim3(64),  0, stream, Wm, pds, flags, whi, wlo);
        hipLaunchKernelGGL(router_4t,  dim3(T / MT), dim3(512), 0, stream, x, whi, wlo, out, flags);
        hipLaunchKernelGGL(router_fix, dim3(128),    dim3(256), 0, stream, x, pds, Wm, out, flags);
        // ---- diagnostic ablations (junk into d_ws, after fix; output unaffected) ----
        if (ws_size >= ABL_SCRATCH_OFF + (2u << 20)) {
            float* junk = (float*)((char*)d_ws + ABL_SCRATCH_OFF);
            hipLaunchKernelGGL(abl_x,   dim3(T / MT), dim3(512), 0, stream, x, junk);
            hipLaunchKernelGGL(abl_lin, dim3(T / MT), dim3(512), 0, stream, x, junk);
        }
    } else {
        hipLaunchKernelGGL(zero_cnt,   dim3(1),      dim3(64),  0, stream, flags);
        hipLaunchKernelGGL(router_f32, dim3(T / RB), dim3(256), 0, stream, x, pds, Wm, out, flags);
        hipLaunchKernelGGL(router_fix, dim3(128),    dim3(256), 0, stream, x, pds, Wm, out, flags);
    }
}

// Round 15
// 102.363 us; speedup vs baseline: 3.5865x; 3.5865x over previous
//
#include <hip/hip_runtime.h>
#include <math.h>

#define H 2048
#define E 64
#define TAU 1e-6f     // p-gap guard (proven r3/5-r14): logit err ~2.5e-7 -> p err ~4e-9 << TAU

// ---- MFMA path geometry ----
#define MT 64         // rows per block -> grid 256 = 1 block/CU, 8 waves

// ---- round-5 fallback geometry ----
#define RB 16
#define CB 512
#define NCH (H / CB)
#define PITCH 516

// d_ws layout
#define WHI_OFF 65792u                     // after flags (65540 B), 256-aligned
#define WFRAG_BYTES 262144u                // 64kc * 4n * 64lane * 8 bf16 * 2B
#define WLO_OFF (WHI_OFF + WFRAG_BYTES)
#define WS_NEEDED ((size_t)(WLO_OFF + WFRAG_BYTES))   // 590080

typedef __attribute__((ext_vector_type(8))) short short8;
typedef __attribute__((ext_vector_type(4))) float f32x4;

__device__ __forceinline__ unsigned short bf16_rne(float f) {
    unsigned u = __float_as_uint(f);
    unsigned r = u + 0x7fffu + ((u >> 16) & 1u);
    return (unsigned short)(r >> 16);
}

// ============ kernel P: W' = pds*W (f64), split into bf16 hi/lo B-fragments ============
__global__ __launch_bounds__(64)
void prep_w(const float* __restrict__ Wm, const float* __restrict__ pds,
            int* __restrict__ flags,
            unsigned short* __restrict__ whi, unsigned short* __restrict__ wlo)
{
    const int fb   = blockIdx.x;        // 0..255 = kc*4 + n
    const int lane = threadIdx.x;       // 0..63
    if (fb == 0 && lane == 0) flags[0] = 0;
    const int kc  = fb >> 2;
    const int n   = fb & 3;
    const int r0  = kc * 32 + (lane >> 4) * 8;
    const int col = n * 16 + (lane & 15);

    short8 hv, lv;
#pragma unroll
    for (int j = 0; j < 8; ++j) {
        const int r = r0 + j;
        const double w = (double)pds[r] * (double)Wm[r * E + col];  // exact in f64
        const unsigned short hb = bf16_rne((float)w);
        const double hd = (double)__uint_as_float((unsigned)hb << 16);
        const unsigned short lb = bf16_rne((float)(w - hd));
        hv[j] = (short)hb;
        lv[j] = (short)lb;
    }
    const size_t off = ((size_t)fb * 64 + lane) * 8;
    *(short8*)(whi + off) = hv;
    *(short8*)(wlo + off) = lv;
}

// ============ kernel M: pipelined 4-tile W-amortized MFMA router ============
// r14 ablation: r13's x pattern pure-load floor = 28.8us (4.4 TB/s), router = ~65us
// -> ~36us of NON-OVERLAPPED compute. The compiler does not software-pipeline
// (r10: VGPR=40). Fix: explicit 2-deep x register double-buffer (fA/fB), issue
// kl+1's 8 dwordx4 into the idle buffer BEFORE convert+MFMA of kl. ~216 VGPR
// under (512,2)'s 256 cap. Numerics byte-identical to r13 (verified absmax 0.0).
__global__ __launch_bounds__(512, 2)
void router_pl(const float* __restrict__ x,
               const unsigned short* __restrict__ whi,
               const unsigned short* __restrict__ wlo,
               float* __restrict__ out,
               int* __restrict__ flags)
{
    __shared__ float lbuf[4][MT * E];   // partial logits (two-stage merge), 64 KB
    __shared__ float ssbuf[8][MT];      // per-wave sum(x^2) partials
    __shared__ float sfac[MT];

    const int t    = threadIdx.x;
    const int wid  = t >> 6;            // 0..7, owns kc in [wid*8, wid*8+8)
    const int lane = t & 63;
    const int lsub = lane & 15;         // A-frag row-in-tile
    const int lgrp = lane >> 4;         // A-frag k-group
    const int row0 = blockIdx.x * MT;

    f32x4 acc[4][4];
#pragma unroll
    for (int a = 0; a < 4; ++a)
#pragma unroll
        for (int b = 0; b < 4; ++b) acc[a][b] = (f32x4){0.f, 0.f, 0.f, 0.f};
    float sq[4] = {0.f, 0.f, 0.f, 0.f};

    const float* xw = x + (size_t)row0 * H + wid * 256 + lgrp * 8;

    // x double-buffer: fX[tt*2+half] (8 float4 each)
    float4 fA[8], fB[8];

    // prologue: kl=0 -> fA
#pragma unroll
    for (int tt = 0; tt < 4; ++tt) {
        const float* p = xw + (size_t)(tt * 16 + lsub) * H;
        fA[tt * 2]     = *(const float4*)p;
        fA[tt * 2 + 1] = *(const float4*)(p + 4);
    }

    auto step = [&](int kl, float4 (&CUR)[8], float4 (&NXT)[8]) {
        // [1] issue next step's x loads into the idle buffer (latency hides
        //     under this step's W-load wait + convert + MFMA)
        const int kn = (kl + 1 < 8) ? kl + 1 : 7;
#pragma unroll
        for (int tt = 0; tt < 4; ++tt) {
            const float* p = xw + (size_t)(tt * 16 + lsub) * H + kn * 32;
            NXT[tt * 2]     = *(const float4*)p;
            NXT[tt * 2 + 1] = *(const float4*)(p + 4);
        }

        // [2] W' fragment batch for this kc (8 coalesced 1KB loads, L2-hot)
        const int kc = wid * 8 + kl;
        const unsigned short* ph = whi + ((size_t)kc * 256 + lane) * 8;
        const unsigned short* pl = wlo + ((size_t)kc * 256 + lane) * 8;
        short8 WH[4], WL[4];
#pragma unroll
        for (int n = 0; n < 4; ++n) {
            WH[n] = *(const short8*)(ph + n * 512);
            WL[n] = *(const short8*)(pl + n * 512);
        }

        // [3] convert CUR -> bf16 hi/lo, accumulate sum(x^2)
        short8 AH[4], AL[4];
#pragma unroll
        for (int tt = 0; tt < 4; ++tt) {
            const float f[8] = { CUR[tt*2].x, CUR[tt*2].y, CUR[tt*2].z, CUR[tt*2].w,
                                 CUR[tt*2+1].x, CUR[tt*2+1].y, CUR[tt*2+1].z, CUR[tt*2+1].w };
            sq[tt] += f[0]*f[0] + f[1]*f[1] + f[2]*f[2] + f[3]*f[3]
                    + f[4]*f[4] + f[5]*f[5] + f[6]*f[6] + f[7]*f[7];
#pragma unroll
            for (int e = 0; e < 8; ++e) {
                const unsigned short hb = bf16_rne(f[e]);
                const unsigned short lb = bf16_rne(f[e] - __uint_as_float((unsigned)hb << 16));
                AH[tt][e] = (short)hb;
                AL[tt][e] = (short)lb;
            }
        }

        // [4] 48 MFMA (one W batch feeds 4 tiles)
#pragma unroll
        for (int tt = 0; tt < 4; ++tt)
#pragma unroll
            for (int n = 0; n < 4; ++n) {
                acc[tt][n] = __builtin_amdgcn_mfma_f32_16x16x32_bf16(AH[tt], WH[n], acc[tt][n], 0, 0, 0);
                acc[tt][n] = __builtin_amdgcn_mfma_f32_16x16x32_bf16(AH[tt], WL[n], acc[tt][n], 0, 0, 0);
                acc[tt][n] = __builtin_amdgcn_mfma_f32_16x16x32_bf16(AL[tt], WH[n], acc[tt][n], 0, 0, 0);
            }
    };

    for (int kl = 0; kl < 8; kl += 2) {
        step(kl,     fA, fB);
        step(kl + 1, fB, fA);
    }

    // ---- sum(x^2): fold lanes sharing lsub (lgrp axis), store per-wave ----
#pragma unroll
    for (int tt = 0; tt < 4; ++tt) {
        float s = sq[tt];
        s += __shfl_xor(s, 16);
        s += __shfl_xor(s, 32);
        if (lane < 16) ssbuf[wid][tt * 16 + lane] = s;
    }

    // ---- partial logits, two-stage merge (C frag: col=lane&15, row=(lane>>4)*4+q) ----
    if (wid < 4) {
#pragma unroll
        for (int tt = 0; tt < 4; ++tt)
#pragma unroll
            for (int n = 0; n < 4; ++n)
#pragma unroll
                for (int q = 0; q < 4; ++q)
                    lbuf[wid][(tt * 16 + lgrp * 4 + q) * E + n * 16 + lsub] = acc[tt][n][q];
    }
    __syncthreads();
    if (wid >= 4) {
#pragma unroll
        for (int tt = 0; tt < 4; ++tt)
#pragma unroll
            for (int n = 0; n < 4; ++n)
#pragma unroll
                for (int q = 0; q < 4; ++q)
                    lbuf[wid - 4][(tt * 16 + lgrp * 4 + q) * E + n * 16 + lsub] += acc[tt][n][q];
    }
    __syncthreads();

    if (t < MT) {
        const float tot = ssbuf[0][t] + ssbuf[1][t] + ssbuf[2][t] + ssbuf[3][t]
                        + ssbuf[4][t] + ssbuf[5][t] + ssbuf[6][t] + ssbuf[7][t];
        sfac[t] = rsqrtf(tot * (1.0f / (float)H) + 1e-6f) * 0.022097086912079608f;
    }
    __syncthreads();

    // ---- epilogue (verified r5-r14): wave wid owns rows wid*8..+7; lane=expert ----
#pragma unroll
    for (int rr = 0; rr < 8; ++rr) {
        const int r = wid * 8 + rr;
        const float L = (lbuf[0][r * E + lane] + lbuf[1][r * E + lane]
                       + lbuf[2][r * E + lane] + lbuf[3][r * E + lane]) * sfac[r];

        float m = L;
#pragma unroll
        for (int off = 32; off >= 1; off >>= 1)
            m = fmaxf(m, __shfl_xor(m, off));
        const float ev = expf(L - m);
        float S = ev;
#pragma unroll
        for (int off = 32; off >= 1; off >>= 1)
            S += __shfl_xor(S, off);
        const float p = ev / S;

        float v1 = p; int i1 = lane;
#pragma unroll
        for (int off = 32; off >= 1; off >>= 1) {
            const float ov = __shfl_xor(v1, off);
            const int   oi = __shfl_xor(i1, off);
            if (ov > v1 || (ov == v1 && oi < i1)) { v1 = ov; i1 = oi; }
        }
        float v2 = (lane == i1) ? -1.0f : p; int i2 = lane;
#pragma unroll
        for (int off = 32; off >= 1; off >>= 1) {
            const float ov = __shfl_xor(v2, off);
            const int   oi = __shfl_xor(i2, off);
            if (ov > v2 || (ov == v2 && oi < i2)) { v2 = ov; i2 = oi; }
        }
        float v3 = (lane == i1 || lane == i2) ? -1.0f : p;
#pragma unroll
        for (int off = 32; off >= 1; off >>= 1)
            v3 = fmaxf(v3, __shfl_xor(v3, off));

        if (lane == 0 && (v2 - v3) < TAU) {
            const int k = atomicAdd(flags, 1);
            flags[1 + k] = row0 + r;
        }

        const float denom = fmaxf(v1 + v2, 1e-9f);
        const float wA = v1 / denom;
        const float wB = v2 / denom;
        const float o  = (lane == i1) ? wA : ((lane == i2) ? wB : 0.0f);
        out[(size_t)(row0 + r) * E + lane] = o;
    }
}

// ============ kernel F: exact-f64 repair of flagged rows (round-3 proven) ============
__global__ __launch_bounds__(256)
void router_fix(const float* __restrict__ x,
                const float* __restrict__ pds,
                const float* __restrict__ Wm,
                float* __restrict__ out,
                const int* __restrict__ flags)
{
    __shared__ double yd[H];
    __shared__ double parts[4 * E];
    __shared__ double ss[256];

    const int t = threadIdx.x;
    const int count = flags[0];

    for (int j = blockIdx.x; j < count; j += gridDim.x) {
        const int r = flags[1 + j];
        const float* xr = x + (size_t)r * H;

        double s = 0.0;
#pragma unroll
        for (int i = 0; i < 8; ++i) {
            const int h = t * 8 + i;
            const double xv = (double)xr[h];
            s += xv * xv;
            yd[h] = xv * (double)pds[h];
        }
        ss[t] = s;
        __syncthreads();

        const int ex = t & 63;
        const int sl = t >> 6;
        const float* wp = Wm + (size_t)(sl * 512) * E + ex;
        double acc = 0.0;
#pragma unroll 8
        for (int h = 0; h < 512; ++h)
            acc = fma(yd[sl * 512 + h], (double)wp[(size_t)h * E], acc);
        parts[sl * E + ex] = acc;
        __syncthreads();

        if (t < 64) {
            const int lane = t;
            double tot = ss[lane * 4] + ss[lane * 4 + 1] + ss[lane * 4 + 2] + ss[lane * 4 + 3];
#pragma unroll
            for (int off = 32; off >= 1; off >>= 1)
                tot += __shfl_xor(tot, off);
            const double sf = (1.0 / sqrt(tot * (1.0 / (double)H) + 1e-6)) * 0.022097086912079608;

            const double Ld = parts[0 * E + lane] + parts[1 * E + lane]
                            + parts[2 * E + lane] + parts[3 * E + lane];
            const float L = (float)(Ld * sf);

            float m = L;
#pragma unroll
            for (int off = 32; off >= 1; off >>= 1)
                m = fmaxf(m, __shfl_xor(m, off));
            const float ev = (float)exp((double)(L - m));
            float S = ev;
#pragma unroll
            for (int off = 32; off >= 1; off >>= 1)
                S += __shfl_xor(S, off);
            const float p = ev / S;

            float v1 = p; int i1 = lane;
#pragma unroll
            for (int off = 32; off >= 1; off >>= 1) {
                const float ov = __shfl_xor(v1, off);
                const int   oi = __shfl_xor(i1, off);
                if (ov > v1 || (ov == v1 && oi < i1)) { v1 = ov; i1 = oi; }
            }
            float v2 = (lane == i1) ? -1.0f : p; int i2 = lane;
#pragma unroll
            for (int off = 32; off >= 1; off >>= 1) {
                const float ov = __shfl_xor(v2, off);
                const int   oi = __shfl_xor(i2, off);
                if (ov > v2 || (ov == v2 && oi < i2)) { v2 = ov; i2 = oi; }
            }

            const float denom = fmaxf(v1 + v2, 1e-9f);
            const float wA = v1 / denom;
            const float wB = v2 / denom;
            const float o  = (lane == i1) ? wA : ((lane == i2) ? wB : 0.0f);
            out[(size_t)r * E + lane] = o;
        }
        __syncthreads();
    }
}

// ============ round-5 fallback (verified) in case ws_size is small ============
__global__ void zero_cnt(int* __restrict__ flags) {
    if (threadIdx.x == 0 && blockIdx.x == 0) flags[0] = 0;
}

__global__ __launch_bounds__(256)
void router_f32(const float* __restrict__ x,
                const float* __restrict__ pds,
                const float* __restrict__ Wm,
                float* __restrict__ out,
                int* __restrict__ flags)
{
    __shared__ __align__(16) float yb[RB * PITCH];
    __shared__ float ssbuf[256];
    __shared__ float sfac[RB];

    const int t    = threadIdx.x;
    const int wv_i = t >> 6;
    const int lane = t & 63;
    const int g    = lane >> 4;
    const int e0   = (lane & 15) << 2;

    const int row0 = blockIdx.x * RB;
    const int srow = t >> 4;
    const int sseg = t & 15;

    const float* xrow = x + (size_t)(row0 + srow) * H;

    float acc[4][4];
#pragma unroll
    for (int a = 0; a < 4; ++a)
#pragma unroll
        for (int b = 0; b < 4; ++b) acc[a][b] = 0.0f;

    float sumsq = 0.0f;
    float4 xv[8];
#pragma unroll
    for (int i = 0; i < 8; ++i)
        xv[i] = *(const float4*)(xrow + sseg * 4 + i * 64);

    for (int c = 0; c < NCH; ++c) {
        const float* pbase = pds + c * CB;
#pragma unroll
        for (int i = 0; i < 8; ++i) {
            const int hl = sseg * 4 + i * 64;
            const float4 a4 = xv[i];
            const float4 p4 = *(const float4*)(pbase + hl);
            sumsq += a4.x * a4.x + a4.y * a4.y + a4.z * a4.z + a4.w * a4.w;
            float4 y4;
            y4.x = a4.x * p4.x; y4.y = a4.y * p4.y;
            y4.z = a4.z * p4.z; y4.w = a4.w * p4.w;
            *(float4*)(&yb[srow * PITCH + hl]) = y4;
        }
        __syncthreads();

        if (c + 1 < NCH) {
            const int h0n = (c + 1) * CB;
#pragma unroll
            for (int i = 0; i < 8; ++i)
                xv[i] = *(const float4*)(xrow + h0n + sseg * 4 + i * 64);
        }

        const int hb = wv_i * 128;
        const float* wbase = Wm + (size_t)(c * CB) * E + e0;
#pragma unroll 2
        for (int s = 0; s < 32; ++s) {
            const int hh = hb + s * 4;
            const float4 w0 = *(const float4*)(wbase + (size_t)(hh + 0) * E);
            const float4 w1 = *(const float4*)(wbase + (size_t)(hh + 1) * E);
            const float4 w2 = *(const float4*)(wbase + (size_t)(hh + 2) * E);
            const float4 w3 = *(const float4*)(wbase + (size_t)(hh + 3) * E);
#pragma unroll
            for (int rr = 0; rr < 4; ++rr) {
                const float4 y4 = *(const float4*)(&yb[(4 * rr + g) * PITCH + hh]);
                acc[rr][0] = fmaf(y4.w, w3.x, fmaf(y4.z, w2.x, fmaf(y4.y, w1.x, fmaf(y4.x, w0.x, acc[rr][0]))));
                acc[rr][1] = fmaf(y4.w, w3.y, fmaf(y4.z, w2.y, fmaf(y4.y, w1.y, fmaf(y4.x, w0.y, acc[rr][1]))));
                acc[rr][2] = fmaf(y4.w, w3.z, fmaf(y4.z, w2.z, fmaf(y4.y, w1.z, fmaf(y4.x, w0.z, acc[rr][2]))));
                acc[rr][3] = fmaf(y4.w, w3.w, fmaf(y4.z, w2.w, fmaf(y4.y, w1.w, fmaf(y4.x, w0.w, acc[rr][3]))));
            }
        }
        __syncthreads();
    }

    ssbuf[t] = sumsq;
    __syncthreads();
    if (t < RB) {
        float tot = 0.0f;
#pragma unroll
        for (int i = 0; i < 16; ++i) tot += ssbuf[t * 16 + i];
        sfac[t] = rsqrtf(tot * (1.0f / (float)H) + 1e-6f) * 0.022097086912079608f;
    }

#pragma unroll
    for (int rr = 0; rr < 4; ++rr) {
        const int r = 4 * rr + g;
        *(float4*)(&yb[((wv_i * RB) + r) * E + e0]) =
            make_float4(acc[rr][0], acc[rr][1], acc[rr][2], acc[rr][3]);
    }
    __syncthreads();

#pragma unroll
    for (int rr = 0; rr < 4; ++rr) {
        const int r = wv_i * 4 + rr;
        float L = yb[(0 * RB + r) * E + lane] + yb[(1 * RB + r) * E + lane]
                + yb[(2 * RB + r) * E + lane] + yb[(3 * RB + r) * E + lane];
        L *= sfac[r];

        float m = L;
#pragma unroll
        for (int off = 32; off >= 1; off >>= 1)
            m = fmaxf(m, __shfl_xor(m, off));
        const float ev = expf(L - m);
        float S = ev;
#pragma unroll
        for (int off = 32; off >= 1; off >>= 1)
            S += __shfl_xor(S, off);
        const float p = ev / S;

        float v1 = p; int i1 = lane;
#pragma unroll
        for (int off = 32; off >= 1; off >>= 1) {
            const float ov = __shfl_xor(v1, off);
            const int   oi = __shfl_xor(i1, off);
            if (ov > v1 || (ov == v1 && oi < i1)) { v1 = ov; i1 = oi; }
        }
        float v2 = (lane == i1) ? -1.0f : p; int i2 = lane;
#pragma unroll
        for (int off = 32; off >= 1; off >>= 1) {
            const float ov = __shfl_xor(v2, off);
            const int   oi = __shfl_xor(i2, off);
            if (ov > v2 || (ov == v2 && oi < i2)) { v2 = ov; i2 = oi; }
        }
        float v3 = (lane == i1 || lane == i2) ? -1.0f : p;
#pragma unroll
        for (int off = 32; off >= 1; off >>= 1)
            v3 = fmaxf(v3, __shfl_xor(v3, off));

        if (lane == 0 && (v2 - v3) < TAU) {
            const int k = atomicAdd(flags, 1);
            flags[1 + k] = row0 + r;
        }

        const float denom = fmaxf(v1 + v2, 1e-9f);
        const float wA = v1 / denom;
        const float wB = v2 / denom;
        const float o  = (lane == i1) ? wA : ((lane == i2) ? wB : 0.0f);
        out[(size_t)(row0 + r) * E + lane] = o;
    }
}

extern "C" void kernel_launch(void* const* d_in, const int* in_sizes, int n_in,
                              void* d_out, int out_size, void* d_ws, size_t ws_size,
                              hipStream_t stream) {
    const float* x   = (const float*)d_in[0];
    const float* pds = (const float*)d_in[1];
    const float* Wm  = (const float*)d_in[2];
    float* out = (float*)d_out;
    int* flags = (int*)d_ws;

    const int T = in_sizes[0] / H;   // 16384

    if (ws_size >= WS_NEEDED) {
        unsigned short* whi = (unsigned short*)((char*)d_ws + WHI_OFF);
        unsigned short* wlo = (unsigned short*)((char*)d_ws + WLO_OFF);
        hipLaunchKernelGGL(prep_w,     dim3(256),    dim3(64),  0, stream, Wm, pds, flags, whi, wlo);
        hipLaunchKernelGGL(router_pl,  dim3(T / MT), dim3(512), 0, stream, x, whi, wlo, out, flags);
        hipLaunchKernelGGL(router_fix, dim3(128),    dim3(256), 0, stream, x, pds, Wm, out, flags);
    } else {
        hipLaunchKernelGGL(zero_cnt,   dim3(1),      dim3(64),  0, stream, flags);
        hipLaunchKernelGGL(router_f32, dim3(T / RB), dim3(256), 0, stream, x, pds, Wm, out, flags);
        hipLaunchKernelGGL(router_fix, dim3(128),    dim3(256), 0, stream, x, pds, Wm, out, flags);
    }
}

// Round 16
// 90.643 us; speedup vs baseline: 4.0502x; 1.1293x over previous
//
#include <hip/hip_runtime.h>
#include <math.h>

#define H 2048
#define E 64
#define TAU 1e-6f     // p-gap guard (proven r3/5-r15): logit err ~2.5e-7 -> p err ~4e-9 << TAU

// ---- MFMA path geometry ----
#define MT 64         // rows per block -> grid 256 = 1 block/CU, 8 waves

// ---- round-5 fallback geometry ----
#define RB 16
#define CB 512
#define NCH (H / CB)
#define PITCH 516

// d_ws layout
#define WHI_OFF 65792u                     // after flags (65540 B), 256-aligned
#define WFRAG_BYTES 262144u                // 64kc * 4n * 64lane * 8 bf16 * 2B
#define WLO_OFF (WHI_OFF + WFRAG_BYTES)
#define WS_NEEDED ((size_t)(WLO_OFF + WFRAG_BYTES))   // 590080

typedef __attribute__((ext_vector_type(8))) short short8;
typedef __attribute__((ext_vector_type(4))) float f32x4;

__device__ __forceinline__ unsigned short bf16_rne(float f) {
    unsigned u = __float_as_uint(f);
    unsigned r = u + 0x7fffu + ((u >> 16) & 1u);
    return (unsigned short)(r >> 16);
}

// ============ kernel P: W' = pds*W (f64), split into bf16 hi/lo B-fragments ============
__global__ __launch_bounds__(64)
void prep_w(const float* __restrict__ Wm, const float* __restrict__ pds,
            int* __restrict__ flags,
            unsigned short* __restrict__ whi, unsigned short* __restrict__ wlo)
{
    const int fb   = blockIdx.x;        // 0..255 = kc*4 + n
    const int lane = threadIdx.x;       // 0..63
    if (fb == 0 && lane == 0) flags[0] = 0;
    const int kc  = fb >> 2;
    const int n   = fb & 3;
    const int r0  = kc * 32 + (lane >> 4) * 8;
    const int col = n * 16 + (lane & 15);

    short8 hv, lv;
#pragma unroll
    for (int j = 0; j < 8; ++j) {
        const int r = r0 + j;
        const double w = (double)pds[r] * (double)Wm[r * E + col];  // exact in f64
        const unsigned short hb = bf16_rne((float)w);
        const double hd = (double)__uint_as_float((unsigned)hb << 16);
        const unsigned short lb = bf16_rne((float)(w - hd));
        hv[j] = (short)hb;
        lv[j] = (short)lb;
    }
    const size_t off = ((size_t)fb * 64 + lane) * 8;
    *(short8*)(whi + off) = hv;
    *(short8*)(wlo + off) = lv;
}

// ============ kernel M: properly-rotated pipelined 4-tile MFMA router ============
// r15 failure analysis: (a) x issued BEFORE W -> waiting for W (newest) drains
// the x prefetch too (in-order vmcnt) => forced serialization; (b) compiler SANK
// the prefetch loads (VGPR=104 < 224 demand). Fix: rotate NEXT{W then x} issue
// at step top, compute CURRENT purely from registers, pin with sched_barrier(0)
// right after the issue section. CUR loads' vmcnt wait lands after a full
// compute phase -> ~900cy HBM latency hidden. Otherwise byte-identical to r13.
__global__ __launch_bounds__(512, 2)
void router_pp(const float* __restrict__ x,
               const unsigned short* __restrict__ whi,
               const unsigned short* __restrict__ wlo,
               float* __restrict__ out,
               int* __restrict__ flags)
{
    __shared__ float lbuf[4][MT * E];   // partial logits (two-stage merge), 64 KB
    __shared__ float ssbuf[8][MT];      // per-wave sum(x^2) partials
    __shared__ float sfac[MT];

    const int t    = threadIdx.x;
    const int wid  = t >> 6;            // 0..7, owns kc in [wid*8, wid*8+8)
    const int lane = t & 63;
    const int lsub = lane & 15;         // A-frag row-in-tile
    const int lgrp = lane >> 4;         // A-frag k-group
    const int row0 = blockIdx.x * MT;

    f32x4 acc[4][4];
#pragma unroll
    for (int a = 0; a < 4; ++a)
#pragma unroll
        for (int b = 0; b < 4; ++b) acc[a][b] = (f32x4){0.f, 0.f, 0.f, 0.f};
    float sq[4] = {0.f, 0.f, 0.f, 0.f};

    const float* xw = x + (size_t)row0 * H + wid * 256 + lgrp * 8;
    const size_t kc0 = (size_t)(wid * 8);

    // double buffers: A = current, B = next (named, static — rule #20)
    short8 WHa[4], WLa[4], WHb[4], WLb[4];
    float4 fa[8], fb[8];

    // prologue: load step 0 into A (W first, then x; drain before loop)
    {
        const unsigned short* ph = whi + (kc0 * 256 + lane) * 8;
        const unsigned short* pl = wlo + (kc0 * 256 + lane) * 8;
#pragma unroll
        for (int n = 0; n < 4; ++n) {
            WHa[n] = *(const short8*)(ph + n * 512);
            WLa[n] = *(const short8*)(pl + n * 512);
        }
#pragma unroll
        for (int tt = 0; tt < 4; ++tt) {
            const float* p = xw + (size_t)(tt * 16 + lsub) * H;
            fa[tt * 2]     = *(const float4*)p;
            fa[tt * 2 + 1] = *(const float4*)(p + 4);
        }
    }

    auto step = [&](int kl, short8 (&CWH)[4], short8 (&CWL)[4], float4 (&CX)[8],
                            short8 (&NWH)[4], short8 (&NWL)[4], float4 (&NX)[8]) {
        // [1] issue NEXT step's loads: W first, then x (W older -> its wait
        //     next iter never drains beyond; x wait lands at next convert).
        const int kn = (kl + 1 < 8) ? kl + 1 : 7;
        const size_t kcn = kc0 + kn;
        const unsigned short* ph = whi + (kcn * 256 + lane) * 8;
        const unsigned short* pl = wlo + (kcn * 256 + lane) * 8;
#pragma unroll
        for (int n = 0; n < 4; ++n) {
            NWH[n] = *(const short8*)(ph + n * 512);
            NWL[n] = *(const short8*)(pl + n * 512);
        }
#pragma unroll
        for (int tt = 0; tt < 4; ++tt) {
            const float* p = xw + (size_t)(tt * 16 + lsub) * H + kn * 32;
            NX[tt * 2]     = *(const float4*)p;
            NX[tt * 2 + 1] = *(const float4*)(p + 4);
        }
        // pin: loads may not sink below this point (r15's failure mode)
        __builtin_amdgcn_sched_barrier(0);

        // [2] convert CUR x -> bf16 hi/lo (registers only; wait was amortized)
        short8 AH[4], AL[4];
#pragma unroll
        for (int tt = 0; tt < 4; ++tt) {
            const float f[8] = { CX[tt*2].x, CX[tt*2].y, CX[tt*2].z, CX[tt*2].w,
                                 CX[tt*2+1].x, CX[tt*2+1].y, CX[tt*2+1].z, CX[tt*2+1].w };
            sq[tt] += f[0]*f[0] + f[1]*f[1] + f[2]*f[2] + f[3]*f[3]
                    + f[4]*f[4] + f[5]*f[5] + f[6]*f[6] + f[7]*f[7];
#pragma unroll
            for (int e = 0; e < 8; ++e) {
                const unsigned short hb = bf16_rne(f[e]);
                const unsigned short lb = bf16_rne(f[e] - __uint_as_float((unsigned)hb << 16));
                AH[tt][e] = (short)hb;
                AL[tt][e] = (short)lb;
            }
        }

        // [3] 48 MFMA from CUR W (registers only)
#pragma unroll
        for (int tt = 0; tt < 4; ++tt)
#pragma unroll
            for (int n = 0; n < 4; ++n) {
                acc[tt][n] = __builtin_amdgcn_mfma_f32_16x16x32_bf16(AH[tt], CWH[n], acc[tt][n], 0, 0, 0);
                acc[tt][n] = __builtin_amdgcn_mfma_f32_16x16x32_bf16(AH[tt], CWL[n], acc[tt][n], 0, 0, 0);
                acc[tt][n] = __builtin_amdgcn_mfma_f32_16x16x32_bf16(AL[tt], CWH[n], acc[tt][n], 0, 0, 0);
            }
        __builtin_amdgcn_sched_barrier(0);
    };

    for (int kl = 0; kl < 8; kl += 2) {
        step(kl,     WHa, WLa, fa, WHb, WLb, fb);
        step(kl + 1, WHb, WLb, fb, WHa, WLa, fa);
    }

    // ---- sum(x^2): fold lanes sharing lsub (lgrp axis), store per-wave ----
#pragma unroll
    for (int tt = 0; tt < 4; ++tt) {
        float s = sq[tt];
        s += __shfl_xor(s, 16);
        s += __shfl_xor(s, 32);
        if (lane < 16) ssbuf[wid][tt * 16 + lane] = s;
    }

    // ---- partial logits, two-stage merge (C frag: col=lane&15, row=(lane>>4)*4+q) ----
    if (wid < 4) {
#pragma unroll
        for (int tt = 0; tt < 4; ++tt)
#pragma unroll
            for (int n = 0; n < 4; ++n)
#pragma unroll
                for (int q = 0; q < 4; ++q)
                    lbuf[wid][(tt * 16 + lgrp * 4 + q) * E + n * 16 + lsub] = acc[tt][n][q];
    }
    __syncthreads();
    if (wid >= 4) {
#pragma unroll
        for (int tt = 0; tt < 4; ++tt)
#pragma unroll
            for (int n = 0; n < 4; ++n)
#pragma unroll
                for (int q = 0; q < 4; ++q)
                    lbuf[wid - 4][(tt * 16 + lgrp * 4 + q) * E + n * 16 + lsub] += acc[tt][n][q];
    }
    __syncthreads();

    if (t < MT) {
        const float tot = ssbuf[0][t] + ssbuf[1][t] + ssbuf[2][t] + ssbuf[3][t]
                        + ssbuf[4][t] + ssbuf[5][t] + ssbuf[6][t] + ssbuf[7][t];
        sfac[t] = rsqrtf(tot * (1.0f / (float)H) + 1e-6f) * 0.022097086912079608f;
    }
    __syncthreads();

    // ---- epilogue (verified r5-r15): wave wid owns rows wid*8..+7; lane=expert ----
#pragma unroll
    for (int rr = 0; rr < 8; ++rr) {
        const int r = wid * 8 + rr;
        const float L = (lbuf[0][r * E + lane] + lbuf[1][r * E + lane]
                       + lbuf[2][r * E + lane] + lbuf[3][r * E + lane]) * sfac[r];

        float m = L;
#pragma unroll
        for (int off = 32; off >= 1; off >>= 1)
            m = fmaxf(m, __shfl_xor(m, off));
        const float ev = expf(L - m);
        float S = ev;
#pragma unroll
        for (int off = 32; off >= 1; off >>= 1)
            S += __shfl_xor(S, off);
        const float p = ev / S;

        float v1 = p; int i1 = lane;
#pragma unroll
        for (int off = 32; off >= 1; off >>= 1) {
            const float ov = __shfl_xor(v1, off);
            const int   oi = __shfl_xor(i1, off);
            if (ov > v1 || (ov == v1 && oi < i1)) { v1 = ov; i1 = oi; }
        }
        float v2 = (lane == i1) ? -1.0f : p; int i2 = lane;
#pragma unroll
        for (int off = 32; off >= 1; off >>= 1) {
            const float ov = __shfl_xor(v2, off);
            const int   oi = __shfl_xor(i2, off);
            if (ov > v2 || (ov == v2 && oi < i2)) { v2 = ov; i2 = oi; }
        }
        float v3 = (lane == i1 || lane == i2) ? -1.0f : p;
#pragma unroll
        for (int off = 32; off >= 1; off >>= 1)
            v3 = fmaxf(v3, __shfl_xor(v3, off));

        if (lane == 0 && (v2 - v3) < TAU) {
            const int k = atomicAdd(flags, 1);
            flags[1 + k] = row0 + r;
        }

        const float denom = fmaxf(v1 + v2, 1e-9f);
        const float wA = v1 / denom;
        const float wB = v2 / denom;
        const float o  = (lane == i1) ? wA : ((lane == i2) ? wB : 0.0f);
        out[(size_t)(row0 + r) * E + lane] = o;
    }
}

// ============ kernel F: exact-f64 repair of flagged rows (round-3 proven) ============
__global__ __launch_bounds__(256)
void router_fix(const float* __restrict__ x,
                const float* __restrict__ pds,
                const float* __restrict__ Wm,
                float* __restrict__ out,
                const int* __restrict__ flags)
{
    __shared__ double yd[H];
    __shared__ double parts[4 * E];
    __shared__ double ss[256];

    const int t = threadIdx.x;
    const int count = flags[0];

    for (int j = blockIdx.x; j < count; j += gridDim.x) {
        const int r = flags[1 + j];
        const float* xr = x + (size_t)r * H;

        double s = 0.0;
#pragma unroll
        for (int i = 0; i < 8; ++i) {
            const int h = t * 8 + i;
            const double xv = (double)xr[h];
            s += xv * xv;
            yd[h] = xv * (double)pds[h];
        }
        ss[t] = s;
        __syncthreads();

        const int ex = t & 63;
        const int sl = t >> 6;
        const float* wp = Wm + (size_t)(sl * 512) * E + ex;
        double acc = 0.0;
#pragma unroll 8
        for (int h = 0; h < 512; ++h)
            acc = fma(yd[sl * 512 + h], (double)wp[(size_t)h * E], acc);
        parts[sl * E + ex] = acc;
        __syncthreads();

        if (t < 64) {
            const int lane = t;
            double tot = ss[lane * 4] + ss[lane * 4 + 1] + ss[lane * 4 + 2] + ss[lane * 4 + 3];
#pragma unroll
            for (int off = 32; off >= 1; off >>= 1)
                tot += __shfl_xor(tot, off);
            const double sf = (1.0 / sqrt(tot * (1.0 / (double)H) + 1e-6)) * 0.022097086912079608;

            const double Ld = parts[0 * E + lane] + parts[1 * E + lane]
                            + parts[2 * E + lane] + parts[3 * E + lane];
            const float L = (float)(Ld * sf);

            float m = L;
#pragma unroll
            for (int off = 32; off >= 1; off >>= 1)
                m = fmaxf(m, __shfl_xor(m, off));
            const float ev = (float)exp((double)(L - m));
            float S = ev;
#pragma unroll
            for (int off = 32; off >= 1; off >>= 1)
                S += __shfl_xor(S, off);
            const float p = ev / S;

            float v1 = p; int i1 = lane;
#pragma unroll
            for (int off = 32; off >= 1; off >>= 1) {
                const float ov = __shfl_xor(v1, off);
                const int   oi = __shfl_xor(i1, off);
                if (ov > v1 || (ov == v1 && oi < i1)) { v1 = ov; i1 = oi; }
            }
            float v2 = (lane == i1) ? -1.0f : p; int i2 = lane;
#pragma unroll
            for (int off = 32; off >= 1; off >>= 1) {
                const float ov = __shfl_xor(v2, off);
                const int   oi = __shfl_xor(i2, off);
                if (ov > v2 || (ov == v2 && oi < i2)) { v2 = ov; i2 = oi; }
            }

            const float denom = fmaxf(v1 + v2, 1e-9f);
            const float wA = v1 / denom;
            const float wB = v2 / denom;
            const float o  = (lane == i1) ? wA : ((lane == i2) ? wB : 0.0f);
            out[(size_t)r * E + lane] = o;
        }
        __syncthreads();
    }
}

// ============ round-5 fallback (verified) in case ws_size is small ============
__global__ void zero_cnt(int* __restrict__ flags) {
    if (threadIdx.x == 0 && blockIdx.x == 0) flags[0] = 0;
}

__global__ __launch_bounds__(256)
void router_f32(const float* __restrict__ x,
                const float* __restrict__ pds,
                const float* __restrict__ Wm,
                float* __restrict__ out,
                int* __restrict__ flags)
{
    __shared__ __align__(16) float yb[RB * PITCH];
    __shared__ float ssbuf[256];
    __shared__ float sfac[RB];

    const int t    = threadIdx.x;
    const int wv_i = t >> 6;
    const int lane = t & 63;
    const int g    = lane >> 4;
    const int e0   = (lane & 15) << 2;

    const int row0 = blockIdx.x * RB;
    const int srow = t >> 4;
    const int sseg = t & 15;

    const float* xrow = x + (size_t)(row0 + srow) * H;

    float acc[4][4];
#pragma unroll
    for (int a = 0; a < 4; ++a)
#pragma unroll
        for (int b = 0; b < 4; ++b) acc[a][b] = 0.0f;

    float sumsq = 0.0f;
    float4 xv[8];
#pragma unroll
    for (int i = 0; i < 8; ++i)
        xv[i] = *(const float4*)(xrow + sseg * 4 + i * 64);

    for (int c = 0; c < NCH; ++c) {
        const float* pbase = pds + c * CB;
#pragma unroll
        for (int i = 0; i < 8; ++i) {
            const int hl = sseg * 4 + i * 64;
            const float4 a4 = xv[i];
            const float4 p4 = *(const float4*)(pbase + hl);
            sumsq += a4.x * a4.x + a4.y * a4.y + a4.z * a4.z + a4.w * a4.w;
            float4 y4;
            y4.x = a4.x * p4.x; y4.y = a4.y * p4.y;
            y4.z = a4.z * p4.z; y4.w = a4.w * p4.w;
            *(float4*)(&yb[srow * PITCH + hl]) = y4;
        }
        __syncthreads();

        if (c + 1 < NCH) {
            const int h0n = (c + 1) * CB;
#pragma unroll
            for (int i = 0; i < 8; ++i)
                xv[i] = *(const float4*)(xrow + h0n + sseg * 4 + i * 64);
        }

        const int hb = wv_i * 128;
        const float* wbase = Wm + (size_t)(c * CB) * E + e0;
#pragma unroll 2
        for (int s = 0; s < 32; ++s) {
            const int hh = hb + s * 4;
            const float4 w0 = *(const float4*)(wbase + (size_t)(hh + 0) * E);
            const float4 w1 = *(const float4*)(wbase + (size_t)(hh + 1) * E);
            const float4 w2 = *(const float4*)(wbase + (size_t)(hh + 2) * E);
            const float4 w3 = *(const float4*)(wbase + (size_t)(hh + 3) * E);
#pragma unroll
            for (int rr = 0; rr < 4; ++rr) {
                const float4 y4 = *(const float4*)(&yb[(4 * rr + g) * PITCH + hh]);
                acc[rr][0] = fmaf(y4.w, w3.x, fmaf(y4.z, w2.x, fmaf(y4.y, w1.x, fmaf(y4.x, w0.x, acc[rr][0]))));
                acc[rr][1] = fmaf(y4.w, w3.y, fmaf(y4.z, w2.y, fmaf(y4.y, w1.y, fmaf(y4.x, w0.y, acc[rr][1]))));
                acc[rr][2] = fmaf(y4.w, w3.z, fmaf(y4.z, w2.z, fmaf(y4.y, w1.z, fmaf(y4.x, w0.z, acc[rr][2]))));
                acc[rr][3] = fmaf(y4.w, w3.w, fmaf(y4.z, w2.w, fmaf(y4.y, w1.w, fmaf(y4.x, w0.w, acc[rr][3]))));
            }
        }
        __syncthreads();
    }

    ssbuf[t] = sumsq;
    __syncthreads();
    if (t < RB) {
        float tot = 0.0f;
#pragma unroll
        for (int i = 0; i < 16; ++i) tot += ssbuf[t * 16 + i];
        sfac[t] = rsqrtf(tot * (1.0f / (float)H) + 1e-6f) * 0.022097086912079608f;
    }

#pragma unroll
    for (int rr = 0; rr < 4; ++rr) {
        const int r = 4 * rr + g;
        *(float4*)(&yb[((wv_i * RB) + r) * E + e0]) =
            make_float4(acc[rr][0], acc[rr][1], acc[rr][2], acc[rr][3]);
    }
    __syncthreads();

#pragma unroll
    for (int rr = 0; rr < 4; ++rr) {
        const int r = wv_i * 4 + rr;
        float L = yb[(0 * RB + r) * E + lane] + yb[(1 * RB + r) * E + lane]
                + yb[(2 * RB + r) * E + lane] + yb[(3 * RB + r) * E + lane];
        L *= sfac[r];

        float m = L;
#pragma unroll
        for (int off = 32; off >= 1; off >>= 1)
            m = fmaxf(m, __shfl_xor(m, off));
        const float ev = expf(L - m);
        float S = ev;
#pragma unroll
        for (int off = 32; off >= 1; off >>= 1)
            S += __shfl_xor(S, off);
        const float p = ev / S;

        float v1 = p; int i1 = lane;
#pragma unroll
        for (int off = 32; off >= 1; off >>= 1) {
            const float ov = __shfl_xor(v1, off);
            const int   oi = __shfl_xor(i1, off);
            if (ov > v1 || (ov == v1 && oi < i1)) { v1 = ov; i1 = oi; }
        }
        float v2 = (lane == i1) ? -1.0f : p; int i2 = lane;
#pragma unroll
        for (int off = 32; off >= 1; off >>= 1) {
            const float ov = __shfl_xor(v2, off);
            const int   oi = __shfl_xor(i2, off);
            if (ov > v2 || (ov == v2 && oi < i2)) { v2 = ov; i2 = oi; }
        }
        float v3 = (lane == i1 || lane == i2) ? -1.0f : p;
#pragma unroll
        for (int off = 32; off >= 1; off >>= 1)
            v3 = fmaxf(v3, __shfl_xor(v3, off));

        if (lane == 0 && (v2 - v3) < TAU) {
            const int k = atomicAdd(flags, 1);
            flags[1 + k] = row0 + r;
        }

        const float denom = fmaxf(v1 + v2, 1e-9f);
        const float wA = v1 / denom;
        const float wB = v2 / denom;
        const float o  = (lane == i1) ? wA : ((lane == i2) ? wB : 0.0f);
        out[(size_t)(row0 + r) * E + lane] = o;
    }
}

extern "C" void kernel_launch(void* const* d_in, const int* in_sizes, int n_in,
                              void* d_out, int out_size, void* d_ws, size_t ws_size,
                              hipStream_t stream) {
    const float* x   = (const float*)d_in[0];
    const float* pds = (const float*)d_in[1];
    const float* Wm  = (const float*)d_in[2];
    float* out = (float*)d_out;
    int* flags = (int*)d_ws;

    const int T = in_sizes[0] / H;   // 16384

    if (ws_size >= WS_NEEDED) {
        unsigned short* whi = (unsigned short*)((char*)d_ws + WHI_OFF);
        unsigned short* wlo = (unsigned short*)((char*)d_ws + WLO_OFF);
        hipLaunchKernelGGL(prep_w,     dim3(256),    dim3(64),  0, stream, Wm, pds, flags, whi, wlo);
        hipLaunchKernelGGL(router_pp,  dim3(T / MT), dim3(512), 0, stream, x, whi, wlo, out, flags);
        hipLaunchKernelGGL(router_fix, dim3(128),    dim3(256), 0, stream, x, pds, Wm, out, flags);
    } else {
        hipLaunchKernelGGL(zero_cnt,   dim3(1),      dim3(64),  0, stream, flags);
        hipLaunchKernelGGL(router_f32, dim3(T / RB), dim3(256), 0, stream, x, pds, Wm, out, flags);
        hipLaunchKernelGGL(router_fix, dim3(128),    dim3(256), 0, stream, x, pds, Wm, out, flags);
    }
}

// Round 17
// 86.810 us; speedup vs baseline: 4.2291x; 1.0442x over previous
//
#include <hip/hip_runtime.h>
#include <math.h>

#define H 2048
#define E 64
#define TAU 1e-6f     // p-gap guard (proven r3/5-r16): logit err ~2.5e-7 -> p err ~4e-9 << TAU

// ---- MFMA path geometry ----
#define MT 32         // rows per block -> grid 512 = 2 blocks/CU, 4 waves/SIMD (TLP x2 vs r13)

// ---- round-5 fallback geometry ----
#define RB 16
#define CB 512
#define NCH (H / CB)
#define PITCH 516

// d_ws layout
#define WHI_OFF 65792u                     // after flags (65540 B), 256-aligned
#define WFRAG_BYTES 262144u                // 64kc * 4n * 64lane * 8 bf16 * 2B
#define WLO_OFF (WHI_OFF + WFRAG_BYTES)
#define WS_NEEDED ((size_t)(WLO_OFF + WFRAG_BYTES))   // 590080

typedef __attribute__((ext_vector_type(8))) short short8;
typedef __attribute__((ext_vector_type(4))) float f32x4;

__device__ __forceinline__ unsigned short bf16_rne(float f) {
    unsigned u = __float_as_uint(f);
    unsigned r = u + 0x7fffu + ((u >> 16) & 1u);
    return (unsigned short)(r >> 16);
}

// ============ kernel P: W' = pds*W (f64), split into bf16 hi/lo B-fragments ============
// frag elem (kc,n,lane,j) = W'[kc*32 + (lane>>4)*8 + j][n*16 + (lane&15)]
__global__ __launch_bounds__(64)
void prep_w(const float* __restrict__ Wm, const float* __restrict__ pds,
            int* __restrict__ flags,
            unsigned short* __restrict__ whi, unsigned short* __restrict__ wlo)
{
    const int fb   = blockIdx.x;        // 0..255 = kc*4 + n
    const int lane = threadIdx.x;       // 0..63
    if (fb == 0 && lane == 0) flags[0] = 0;
    const int kc  = fb >> 2;
    const int n   = fb & 3;
    const int r0  = kc * 32 + (lane >> 4) * 8;
    const int col = n * 16 + (lane & 15);

    short8 hv, lv;
#pragma unroll
    for (int j = 0; j < 8; ++j) {
        const int r = r0 + j;
        const double w = (double)pds[r] * (double)Wm[r * E + col];  // exact in f64
        const unsigned short hb = bf16_rne((float)w);
        const double hd = (double)__uint_as_float((unsigned)hb << 16);
        const unsigned short lb = bf16_rne((float)(w - hd));
        hv[j] = (short)hb;
        lv[j] = (short)lb;
    }
    const size_t off = ((size_t)fb * 64 + lane) * 8;
    *(short8*)(whi + off) = hv;
    *(short8*)(wlo + off) = lv;
}

// ============ kernel M: 2-tile W-amortized MFMA router (r13 structure, more TLP) ============
// r16 post-mortem: register pipelining is a dead end on this compiler (caps at
// 128 VGPR, spills beyond). r13's plain loop at MT=64 had only 2 waves/SIMD
// (grid 256, Occupancy 20%) -> load latency exposed. This is r13 EXACTLY but
// MT=32: per-wave regs ~96 (fits 128, no spill), grid 512 = 2 blocks/CU =
// 4 waves/SIMD -> waves hide each other's latency. W traffic 128->256 MB
// (measured cost ~3us; r6-r11's 512MB vs r13's 128MB was only ~10us).
__global__ __launch_bounds__(512, 2)
void router_2t(const float* __restrict__ x,
               const unsigned short* __restrict__ whi,
               const unsigned short* __restrict__ wlo,
               float* __restrict__ out,
               int* __restrict__ flags)
{
    __shared__ float lbuf[4][MT * E];   // partial logits (two-stage merge), 32 KB
    __shared__ float ssbuf[8][MT];      // per-wave sum(x^2) partials
    __shared__ float sfac[MT];

    const int t    = threadIdx.x;
    const int wid  = t >> 6;            // 0..7, owns kc in [wid*8, wid*8+8)
    const int lane = t & 63;
    const int lsub = lane & 15;         // A-frag row-in-tile
    const int lgrp = lane >> 4;         // A-frag k-group
    const int row0 = blockIdx.x * MT;

    f32x4 acc[2][4];                    // [tile][n], 32 VGPR, static idx
#pragma unroll
    for (int a = 0; a < 2; ++a)
#pragma unroll
        for (int b = 0; b < 4; ++b) acc[a][b] = (f32x4){0.f, 0.f, 0.f, 0.f};
    float sq[2] = {0.f, 0.f};

    const float* xw = x + (size_t)row0 * H + wid * 256 + lgrp * 8;

    for (int kl = 0; kl < 8; ++kl) {
        const int kc = wid * 8 + kl;

        // W' fragment batch for this kc: 8 coalesced 1KB loads (L2-hot)
        const unsigned short* ph = whi + ((size_t)kc * 256 + lane) * 8;
        const unsigned short* pl = wlo + ((size_t)kc * 256 + lane) * 8;
        short8 WH[4], WL[4];
#pragma unroll
        for (int n = 0; n < 4; ++n) {
            WH[n] = *(const short8*)(ph + n * 512);
            WL[n] = *(const short8*)(pl + n * 512);
        }

        // x frags for 2 row-tiles (lines fully consumed by the a0/a1 pair)
        float4 a0[2], a1[2];
#pragma unroll
        for (int tt = 0; tt < 2; ++tt) {
            const float* p = xw + (size_t)(tt * 16 + lsub) * H + kl * 32;
            a0[tt] = *(const float4*)p;
            a1[tt] = *(const float4*)(p + 4);
        }

        // convert to bf16 hi/lo and accumulate sum(x^2)
        short8 AH[2], AL[2];
#pragma unroll
        for (int tt = 0; tt < 2; ++tt) {
            const float f[8] = { a0[tt].x, a0[tt].y, a0[tt].z, a0[tt].w,
                                 a1[tt].x, a1[tt].y, a1[tt].z, a1[tt].w };
            sq[tt] += f[0]*f[0] + f[1]*f[1] + f[2]*f[2] + f[3]*f[3]
                    + f[4]*f[4] + f[5]*f[5] + f[6]*f[6] + f[7]*f[7];
#pragma unroll
            for (int e = 0; e < 8; ++e) {
                const unsigned short hb = bf16_rne(f[e]);
                const unsigned short lb = bf16_rne(f[e] - __uint_as_float((unsigned)hb << 16));
                AH[tt][e] = (short)hb;
                AL[tt][e] = (short)lb;
            }
        }

        // 2 tiles x 4 n x 3 terms: one W batch feeds 24 MFMAs
#pragma unroll
        for (int tt = 0; tt < 2; ++tt)
#pragma unroll
            for (int n = 0; n < 4; ++n) {
                acc[tt][n] = __builtin_amdgcn_mfma_f32_16x16x32_bf16(AH[tt], WH[n], acc[tt][n], 0, 0, 0);
                acc[tt][n] = __builtin_amdgcn_mfma_f32_16x16x32_bf16(AH[tt], WL[n], acc[tt][n], 0, 0, 0);
                acc[tt][n] = __builtin_amdgcn_mfma_f32_16x16x32_bf16(AL[tt], WH[n], acc[tt][n], 0, 0, 0);
            }
    }

    // ---- sum(x^2): fold lanes sharing lsub (lgrp axis), store per-wave ----
#pragma unroll
    for (int tt = 0; tt < 2; ++tt) {
        float s = sq[tt];
        s += __shfl_xor(s, 16);
        s += __shfl_xor(s, 32);
        if (lane < 16) ssbuf[wid][tt * 16 + lane] = s;
    }

    // ---- partial logits, two-stage merge (C frag: col=lane&15, row=(lane>>4)*4+q) ----
    if (wid < 4) {
#pragma unroll
        for (int tt = 0; tt < 2; ++tt)
#pragma unroll
            for (int n = 0; n < 4; ++n)
#pragma unroll
                for (int q = 0; q < 4; ++q)
                    lbuf[wid][(tt * 16 + lgrp * 4 + q) * E + n * 16 + lsub] = acc[tt][n][q];
    }
    __syncthreads();
    if (wid >= 4) {
#pragma unroll
        for (int tt = 0; tt < 2; ++tt)
#pragma unroll
            for (int n = 0; n < 4; ++n)
#pragma unroll
                for (int q = 0; q < 4; ++q)
                    lbuf[wid - 4][(tt * 16 + lgrp * 4 + q) * E + n * 16 + lsub] += acc[tt][n][q];
    }
    __syncthreads();

    if (t < MT) {
        const float tot = ssbuf[0][t] + ssbuf[1][t] + ssbuf[2][t] + ssbuf[3][t]
                        + ssbuf[4][t] + ssbuf[5][t] + ssbuf[6][t] + ssbuf[7][t];
        sfac[t] = rsqrtf(tot * (1.0f / (float)H) + 1e-6f) * 0.022097086912079608f;
    }
    __syncthreads();

    // ---- epilogue (verified r5-r16): wave wid owns rows wid*4..+3; lane=expert ----
#pragma unroll
    for (int rr = 0; rr < 4; ++rr) {
        const int r = wid * 4 + rr;
        const float L = (lbuf[0][r * E + lane] + lbuf[1][r * E + lane]
                       + lbuf[2][r * E + lane] + lbuf[3][r * E + lane]) * sfac[r];

        float m = L;
#pragma unroll
        for (int off = 32; off >= 1; off >>= 1)
            m = fmaxf(m, __shfl_xor(m, off));
        const float ev = expf(L - m);
        float S = ev;
#pragma unroll
        for (int off = 32; off >= 1; off >>= 1)
            S += __shfl_xor(S, off);
        const float p = ev / S;

        float v1 = p; int i1 = lane;
#pragma unroll
        for (int off = 32; off >= 1; off >>= 1) {
            const float ov = __shfl_xor(v1, off);
            const int   oi = __shfl_xor(i1, off);
            if (ov > v1 || (ov == v1 && oi < i1)) { v1 = ov; i1 = oi; }
        }
        float v2 = (lane == i1) ? -1.0f : p; int i2 = lane;
#pragma unroll
        for (int off = 32; off >= 1; off >>= 1) {
            const float ov = __shfl_xor(v2, off);
            const int   oi = __shfl_xor(i2, off);
            if (ov > v2 || (ov == v2 && oi < i2)) { v2 = ov; i2 = oi; }
        }
        float v3 = (lane == i1 || lane == i2) ? -1.0f : p;
#pragma unroll
        for (int off = 32; off >= 1; off >>= 1)
            v3 = fmaxf(v3, __shfl_xor(v3, off));

        if (lane == 0 && (v2 - v3) < TAU) {
            const int k = atomicAdd(flags, 1);
            flags[1 + k] = row0 + r;
        }

        const float denom = fmaxf(v1 + v2, 1e-9f);
        const float wA = v1 / denom;
        const float wB = v2 / denom;
        const float o  = (lane == i1) ? wA : ((lane == i2) ? wB : 0.0f);
        out[(size_t)(row0 + r) * E + lane] = o;
    }
}

// ============ kernel F: exact-f64 repair of flagged rows (round-3 proven) ============
__global__ __launch_bounds__(256)
void router_fix(const float* __restrict__ x,
                const float* __restrict__ pds,
                const float* __restrict__ Wm,
                float* __restrict__ out,
                const int* __restrict__ flags)
{
    __shared__ double yd[H];
    __shared__ double parts[4 * E];
    __shared__ double ss[256];

    const int t = threadIdx.x;
    const int count = flags[0];

    for (int j = blockIdx.x; j < count; j += gridDim.x) {
        const int r = flags[1 + j];
        const float* xr = x + (size_t)r * H;

        double s = 0.0;
#pragma unroll
        for (int i = 0; i < 8; ++i) {
            const int h = t * 8 + i;
            const double xv = (double)xr[h];
            s += xv * xv;
            yd[h] = xv * (double)pds[h];
        }
        ss[t] = s;
        __syncthreads();

        const int ex = t & 63;
        const int sl = t >> 6;
        const float* wp = Wm + (size_t)(sl * 512) * E + ex;
        double acc = 0.0;
#pragma unroll 8
        for (int h = 0; h < 512; ++h)
            acc = fma(yd[sl * 512 + h], (double)wp[(size_t)h * E], acc);
        parts[sl * E + ex] = acc;
        __syncthreads();

        if (t < 64) {
            const int lane = t;
            double tot = ss[lane * 4] + ss[lane * 4 + 1] + ss[lane * 4 + 2] + ss[lane * 4 + 3];
#pragma unroll
            for (int off = 32; off >= 1; off >>= 1)
                tot += __shfl_xor(tot, off);
            const double sf = (1.0 / sqrt(tot * (1.0 / (double)H) + 1e-6)) * 0.022097086912079608;

            const double Ld = parts[0 * E + lane] + parts[1 * E + lane]
                            + parts[2 * E + lane] + parts[3 * E + lane];
            const float L = (float)(Ld * sf);

            float m = L;
#pragma unroll
            for (int off = 32; off >= 1; off >>= 1)
                m = fmaxf(m, __shfl_xor(m, off));
            const float ev = (float)exp((double)(L - m));
            float S = ev;
#pragma unroll
            for (int off = 32; off >= 1; off >>= 1)
                S += __shfl_xor(S, off);
            const float p = ev / S;

            float v1 = p; int i1 = lane;
#pragma unroll
            for (int off = 32; off >= 1; off >>= 1) {
                const float ov = __shfl_xor(v1, off);
                const int   oi = __shfl_xor(i1, off);
                if (ov > v1 || (ov == v1 && oi < i1)) { v1 = ov; i1 = oi; }
            }
            float v2 = (lane == i1) ? -1.0f : p; int i2 = lane;
#pragma unroll
            for (int off = 32; off >= 1; off >>= 1) {
                const float ov = __shfl_xor(v2, off);
                const int   oi = __shfl_xor(i2, off);
                if (ov > v2 || (ov == v2 && oi < i2)) { v2 = ov; i2 = oi; }
            }

            const float denom = fmaxf(v1 + v2, 1e-9f);
            const float wA = v1 / denom;
            const float wB = v2 / denom;
            const float o  = (lane == i1) ? wA : ((lane == i2) ? wB : 0.0f);
            out[(size_t)r * E + lane] = o;
        }
        __syncthreads();
    }
}

// ============ round-5 fallback (verified) in case ws_size is small ============
__global__ void zero_cnt(int* __restrict__ flags) {
    if (threadIdx.x == 0 && blockIdx.x == 0) flags[0] = 0;
}

__global__ __launch_bounds__(256)
void router_f32(const float* __restrict__ x,
                const float* __restrict__ pds,
                const float* __restrict__ Wm,
                float* __restrict__ out,
                int* __restrict__ flags)
{
    __shared__ __align__(16) float yb[RB * PITCH];
    __shared__ float ssbuf[256];
    __shared__ float sfac[RB];

    const int t    = threadIdx.x;
    const int wv_i = t >> 6;
    const int lane = t & 63;
    const int g    = lane >> 4;
    const int e0   = (lane & 15) << 2;

    const int row0 = blockIdx.x * RB;
    const int srow = t >> 4;
    const int sseg = t & 15;

    const float* xrow = x + (size_t)(row0 + srow) * H;

    float acc[4][4];
#pragma unroll
    for (int a = 0; a < 4; ++a)
#pragma unroll
        for (int b = 0; b < 4; ++b) acc[a][b] = 0.0f;

    float sumsq = 0.0f;
    float4 xv[8];
#pragma unroll
    for (int i = 0; i < 8; ++i)
        xv[i] = *(const float4*)(xrow + sseg * 4 + i * 64);

    for (int c = 0; c < NCH; ++c) {
        const float* pbase = pds + c * CB;
#pragma unroll
        for (int i = 0; i < 8; ++i) {
            const int hl = sseg * 4 + i * 64;
            const float4 a4 = xv[i];
            const float4 p4 = *(const float4*)(pbase + hl);
            sumsq += a4.x * a4.x + a4.y * a4.y + a4.z * a4.z + a4.w * a4.w;
            float4 y4;
            y4.x = a4.x * p4.x; y4.y = a4.y * p4.y;
            y4.z = a4.z * p4.z; y4.w = a4.w * p4.w;
            *(float4*)(&yb[srow * PITCH + hl]) = y4;
        }
        __syncthreads();

        if (c + 1 < NCH) {
            const int h0n = (c + 1) * CB;
#pragma unroll
            for (int i = 0; i < 8; ++i)
                xv[i] = *(const float4*)(xrow + h0n + sseg * 4 + i * 64);
        }

        const int hb = wv_i * 128;
        const float* wbase = Wm + (size_t)(c * CB) * E + e0;
#pragma unroll 2
        for (int s = 0; s < 32; ++s) {
            const int hh = hb + s * 4;
            const float4 w0 = *(const float4*)(wbase + (size_t)(hh + 0) * E);
            const float4 w1 = *(const float4*)(wbase + (size_t)(hh + 1) * E);
            const float4 w2 = *(const float4*)(wbase + (size_t)(hh + 2) * E);
            const float4 w3 = *(const float4*)(wbase + (size_t)(hh + 3) * E);
#pragma unroll
            for (int rr = 0; rr < 4; ++rr) {
                const float4 y4 = *(const float4*)(&yb[(4 * rr + g) * PITCH + hh]);
                acc[rr][0] = fmaf(y4.w, w3.x, fmaf(y4.z, w2.x, fmaf(y4.y, w1.x, fmaf(y4.x, w0.x, acc[rr][0]))));
                acc[rr][1] = fmaf(y4.w, w3.y, fmaf(y4.z, w2.y, fmaf(y4.y, w1.y, fmaf(y4.x, w0.y, acc[rr][1]))));
                acc[rr][2] = fmaf(y4.w, w3.z, fmaf(y4.z, w2.z, fmaf(y4.y, w1.z, fmaf(y4.x, w0.z, acc[rr][2]))));
                acc[rr][3] = fmaf(y4.w, w3.w, fmaf(y4.z, w2.w, fmaf(y4.y, w1.w, fmaf(y4.x, w0.w, acc[rr][3]))));
            }
        }
        __syncthreads();
    }

    ssbuf[t] = sumsq;
    __syncthreads();
    if (t < RB) {
        float tot = 0.0f;
#pragma unroll
        for (int i = 0; i < 16; ++i) tot += ssbuf[t * 16 + i];
        sfac[t] = rsqrtf(tot * (1.0f / (float)H) + 1e-6f) * 0.022097086912079608f;
    }

#pragma unroll
    for (int rr = 0; rr < 4; ++rr) {
        const int r = 4 * rr + g;
        *(float4*)(&yb[((wv_i * RB) + r) * E + e0]) =
            make_float4(acc[rr][0], acc[rr][1], acc[rr][2], acc[rr][3]);
    }
    __syncthreads();

#pragma unroll
    for (int rr = 0; rr < 4; ++rr) {
        const int r = wv_i * 4 + rr;
        float L = yb[(0 * RB + r) * E + lane] + yb[(1 * RB + r) * E + lane]
                + yb[(2 * RB + r) * E + lane] + yb[(3 * RB + r) * E + lane];
        L *= sfac[r];

        float m = L;
#pragma unroll
        for (int off = 32; off >= 1; off >>= 1)
            m = fmaxf(m, __shfl_xor(m, off));
        const float ev = expf(L - m);
        float S = ev;
#pragma unroll
        for (int off = 32; off >= 1; off >>= 1)
            S += __shfl_xor(S, off);
        const float p = ev / S;

        float v1 = p; int i1 = lane;
#pragma unroll
        for (int off = 32; off >= 1; off >>= 1) {
            const float ov = __shfl_xor(v1, off);
            const int   oi = __shfl_xor(i1, off);
            if (ov > v1 || (ov == v1 && oi < i1)) { v1 = ov; i1 = oi; }
        }
        float v2 = (lane == i1) ? -1.0f : p; int i2 = lane;
#pragma unroll
        for (int off = 32; off >= 1; off >>= 1) {
            const float ov = __shfl_xor(v2, off);
            const int   oi = __shfl_xor(i2, off);
            if (ov > v2 || (ov == v2 && oi < i2)) { v2 = ov; i2 = oi; }
        }
        float v3 = (lane == i1 || lane == i2) ? -1.0f : p;
#pragma unroll
        for (int off = 32; off >= 1; off >>= 1)
            v3 = fmaxf(v3, __shfl_xor(v3, off));

        if (lane == 0 && (v2 - v3) < TAU) {
            const int k = atomicAdd(flags, 1);
            flags[1 + k] = row0 + r;
        }

        const float denom = fmaxf(v1 + v2, 1e-9f);
        const float wA = v1 / denom;
        const float wB = v2 / denom;
        const float o  = (lane == i1) ? wA : ((lane == i2) ? wB : 0.0f);
        out[(size_t)(row0 + r) * E + lane] = o;
    }
}

extern "C" void kernel_launch(void* const* d_in, const int* in_sizes, int n_in,
                              void* d_out, int out_size, void* d_ws, size_t ws_size,
                              hipStream_t stream) {
    const float* x   = (const float*)d_in[0];
    const float* pds = (const float*)d_in[1];
    const float* Wm  = (const float*)d_in[2];
    float* out = (float*)d_out;
    int* flags = (int*)d_ws;

    const int T = in_sizes[0] / H;   // 16384

    if (ws_size >= WS_NEEDED) {
        unsigned short* whi = (unsigned short*)((char*)d_ws + WHI_OFF);
        unsigned short* wlo = (unsigned short*)((char*)d_ws + WLO_OFF);
        hipLaunchKernelGGL(prep_w,     dim3(256),    dim3(64),  0, stream, Wm, pds, flags, whi, wlo);
        hipLaunchKernelGGL(router_2t,  dim3(T / MT), dim3(512), 0, stream, x, whi, wlo, out, flags);
        hipLaunchKernelGGL(router_fix, dim3(128),    dim3(256), 0, stream, x, pds, Wm, out, flags);
    } else {
        hipLaunchKernelGGL(zero_cnt,   dim3(1),      dim3(64),  0, stream, flags);
        hipLaunchKernelGGL(router_f32, dim3(T / RB), dim3(256), 0, stream, x, pds, Wm, out, flags);
        hipLaunchKernelGGL(router_fix, dim3(128),    dim3(256), 0, stream, x, pds, Wm, out, flags);
    }
}

// Round 18
// 83.396 us; speedup vs baseline: 4.4022x; 1.0409x over previous
//
#include <hip/hip_runtime.h>
#include <math.h>

#define H 2048
#define E 64
#define TAU 1e-6f     // p-gap guard (proven r3/5-r17): logit err ~2.5e-7 -> p err ~4e-9 << TAU

// ---- MFMA path geometry ----
#define MT 64         // rows per block -> grid 256 = 1 block/CU, 8 waves

// ---- round-5 fallback geometry ----
#define RB 16
#define CB 512
#define NCH (H / CB)
#define PITCH 516

// d_ws layout
#define WHI_OFF 65792u                     // after flags (65540 B), 256-aligned
#define WFRAG_BYTES 262144u                // 64kc * 4n * 64lane * 8 bf16 * 2B
#define WLO_OFF (WHI_OFF + WFRAG_BYTES)
#define WS_NEEDED ((size_t)(WLO_OFF + WFRAG_BYTES))   // 590080

typedef __attribute__((ext_vector_type(8))) short short8;
typedef __attribute__((ext_vector_type(4))) float f32x4;

__device__ __forceinline__ unsigned short bf16_rne(float f) {
    unsigned u = __float_as_uint(f);
    unsigned r = u + 0x7fffu + ((u >> 16) & 1u);
    return (unsigned short)(r >> 16);
}

// ============ kernel P: W' = pds*W (f64), split into bf16 hi/lo B-fragments ============
// frag elem (kc,n,lane,j) = W'[kc*32 + (lane>>4)*8 + j][n*16 + (lane&15)]
__global__ __launch_bounds__(64)
void prep_w(const float* __restrict__ Wm, const float* __restrict__ pds,
            int* __restrict__ flags,
            unsigned short* __restrict__ whi, unsigned short* __restrict__ wlo)
{
    const int fb   = blockIdx.x;        // 0..255 = kc*4 + n
    const int lane = threadIdx.x;       // 0..63
    if (fb == 0 && lane == 0) flags[0] = 0;
    const int kc  = fb >> 2;
    const int n   = fb & 3;
    const int r0  = kc * 32 + (lane >> 4) * 8;
    const int col = n * 16 + (lane & 15);

    short8 hv, lv;
#pragma unroll
    for (int j = 0; j < 8; ++j) {
        const int r = r0 + j;
        const double w = (double)pds[r] * (double)Wm[r * E + col];  // exact in f64
        const unsigned short hb = bf16_rne((float)w);
        const double hd = (double)__uint_as_float((unsigned)hb << 16);
        const unsigned short lb = bf16_rne((float)(w - hd));
        hv[j] = (short)hb;
        lv[j] = (short)lb;
    }
    const size_t off = ((size_t)fb * 64 + lane) * 8;
    *(short8*)(whi + off) = hv;
    *(short8*)(wlo + off) = lv;
}

// ============ kernel M: 4-tile W-amortized MFMA router (r13, best verified: 83.2us) ============
// Session conclusion (r6-r17, 12 structural variants): all land 83-102us; the
// ~30us above the measured 28.8us x-pattern floor is load-latency serialization
// this compiler will not pipeline away (prefetch sunk r10/r15, spilled r16,
// counted-vmcnt defeated r11). This is the empirical fixed point; past it
// requires an inline-asm K-loop (AITER-style manual s_waitcnt scheduling).
__global__ __launch_bounds__(512, 2)
void router_4t(const float* __restrict__ x,
               const unsigned short* __restrict__ whi,
               const unsigned short* __restrict__ wlo,
               float* __restrict__ out,
               int* __restrict__ flags)
{
    __shared__ float lbuf[4][MT * E];   // partial logits (two-stage merge), 64 KB
    __shared__ float ssbuf[8][MT];      // per-wave sum(x^2) partials
    __shared__ float sfac[MT];

    const int t    = threadIdx.x;
    const int wid  = t >> 6;            // 0..7, owns kc in [wid*8, wid*8+8)
    const int lane = t & 63;
    const int lsub = lane & 15;         // A-frag row-in-tile
    const int lgrp = lane >> 4;         // A-frag k-group
    const int row0 = blockIdx.x * MT;

    f32x4 acc[4][4];                    // [tile][n], 64 VGPR, static idx
#pragma unroll
    for (int a = 0; a < 4; ++a)
#pragma unroll
        for (int b = 0; b < 4; ++b) acc[a][b] = (f32x4){0.f, 0.f, 0.f, 0.f};
    float sq[4] = {0.f, 0.f, 0.f, 0.f};

    const float* xw = x + (size_t)row0 * H + wid * 256 + lgrp * 8;

    for (int kl = 0; kl < 8; ++kl) {
        const int kc = wid * 8 + kl;

        // W' fragment batch for this kc: 8 coalesced 1KB loads (L2-hot)
        const unsigned short* ph = whi + ((size_t)kc * 256 + lane) * 8;
        const unsigned short* pl = wlo + ((size_t)kc * 256 + lane) * 8;
        short8 WH[4], WL[4];
#pragma unroll
        for (int n = 0; n < 4; ++n) {
            WH[n] = *(const short8*)(ph + n * 512);
            WL[n] = *(const short8*)(pl + n * 512);
        }

        // x frags for 4 row-tiles (lines fully consumed by the a0/a1 pair)
        float4 a0[4], a1[4];
#pragma unroll
        for (int tt = 0; tt < 4; ++tt) {
            const float* p = xw + (size_t)(tt * 16 + lsub) * H + kl * 32;
            a0[tt] = *(const float4*)p;
            a1[tt] = *(const float4*)(p + 4);
        }

        // convert to bf16 hi/lo and accumulate sum(x^2)
        short8 AH[4], AL[4];
#pragma unroll
        for (int tt = 0; tt < 4; ++tt) {
            const float f[8] = { a0[tt].x, a0[tt].y, a0[tt].z, a0[tt].w,
                                 a1[tt].x, a1[tt].y, a1[tt].z, a1[tt].w };
            sq[tt] += f[0]*f[0] + f[1]*f[1] + f[2]*f[2] + f[3]*f[3]
                    + f[4]*f[4] + f[5]*f[5] + f[6]*f[6] + f[7]*f[7];
#pragma unroll
            for (int e = 0; e < 8; ++e) {
                const unsigned short hb = bf16_rne(f[e]);
                const unsigned short lb = bf16_rne(f[e] - __uint_as_float((unsigned)hb << 16));
                AH[tt][e] = (short)hb;
                AL[tt][e] = (short)lb;
            }
        }

        // 4 tiles x 4 n x 3 terms: one W batch feeds 48 MFMAs
#pragma unroll
        for (int tt = 0; tt < 4; ++tt)
#pragma unroll
            for (int n = 0; n < 4; ++n) {
                acc[tt][n] = __builtin_amdgcn_mfma_f32_16x16x32_bf16(AH[tt], WH[n], acc[tt][n], 0, 0, 0);
                acc[tt][n] = __builtin_amdgcn_mfma_f32_16x16x32_bf16(AH[tt], WL[n], acc[tt][n], 0, 0, 0);
                acc[tt][n] = __builtin_amdgcn_mfma_f32_16x16x32_bf16(AL[tt], WH[n], acc[tt][n], 0, 0, 0);
            }
    }

    // ---- sum(x^2): fold lanes sharing lsub (lgrp axis), store per-wave ----
#pragma unroll
    for (int tt = 0; tt < 4; ++tt) {
        float s = sq[tt];
        s += __shfl_xor(s, 16);
        s += __shfl_xor(s, 32);
        if (lane < 16) ssbuf[wid][tt * 16 + lane] = s;
    }

    // ---- partial logits, two-stage merge (C frag: col=lane&15, row=(lane>>4)*4+q) ----
    if (wid < 4) {
#pragma unroll
        for (int tt = 0; tt < 4; ++tt)
#pragma unroll
            for (int n = 0; n < 4; ++n)
#pragma unroll
                for (int q = 0; q < 4; ++q)
                    lbuf[wid][(tt * 16 + lgrp * 4 + q) * E + n * 16 + lsub] = acc[tt][n][q];
    }
    __syncthreads();
    if (wid >= 4) {
#pragma unroll
        for (int tt = 0; tt < 4; ++tt)
#pragma unroll
            for (int n = 0; n < 4; ++n)
#pragma unroll
                for (int q = 0; q < 4; ++q)
                    lbuf[wid - 4][(tt * 16 + lgrp * 4 + q) * E + n * 16 + lsub] += acc[tt][n][q];
    }
    __syncthreads();

    if (t < MT) {
        const float tot = ssbuf[0][t] + ssbuf[1][t] + ssbuf[2][t] + ssbuf[3][t]
                        + ssbuf[4][t] + ssbuf[5][t] + ssbuf[6][t] + ssbuf[7][t];
        sfac[t] = rsqrtf(tot * (1.0f / (float)H) + 1e-6f) * 0.022097086912079608f;
    }
    __syncthreads();

    // ---- epilogue (verified r5-r17): wave wid owns rows wid*8..+7; lane=expert ----
#pragma unroll
    for (int rr = 0; rr < 8; ++rr) {
        const int r = wid * 8 + rr;
        const float L = (lbuf[0][r * E + lane] + lbuf[1][r * E + lane]
                       + lbuf[2][r * E + lane] + lbuf[3][r * E + lane]) * sfac[r];

        float m = L;
#pragma unroll
        for (int off = 32; off >= 1; off >>= 1)
            m = fmaxf(m, __shfl_xor(m, off));
        const float ev = expf(L - m);
        float S = ev;
#pragma unroll
        for (int off = 32; off >= 1; off >>= 1)
            S += __shfl_xor(S, off);
        const float p = ev / S;

        float v1 = p; int i1 = lane;
#pragma unroll
        for (int off = 32; off >= 1; off >>= 1) {
            const float ov = __shfl_xor(v1, off);
            const int   oi = __shfl_xor(i1, off);
            if (ov > v1 || (ov == v1 && oi < i1)) { v1 = ov; i1 = oi; }
        }
        float v2 = (lane == i1) ? -1.0f : p; int i2 = lane;
#pragma unroll
        for (int off = 32; off >= 1; off >>= 1) {
            const float ov = __shfl_xor(v2, off);
            const int   oi = __shfl_xor(i2, off);
            if (ov > v2 || (ov == v2 && oi < i2)) { v2 = ov; i2 = oi; }
        }
        float v3 = (lane == i1 || lane == i2) ? -1.0f : p;
#pragma unroll
        for (int off = 32; off >= 1; off >>= 1)
            v3 = fmaxf(v3, __shfl_xor(v3, off));

        if (lane == 0 && (v2 - v3) < TAU) {
            const int k = atomicAdd(flags, 1);
            flags[1 + k] = row0 + r;
        }

        const float denom = fmaxf(v1 + v2, 1e-9f);
        const float wA = v1 / denom;
        const float wB = v2 / denom;
        const float o  = (lane == i1) ? wA : ((lane == i2) ? wB : 0.0f);
        out[(size_t)(row0 + r) * E + lane] = o;
    }
}

// ============ kernel F: exact-f64 repair of flagged rows (round-3 proven) ============
__global__ __launch_bounds__(256)
void router_fix(const float* __restrict__ x,
                const float* __restrict__ pds,
                const float* __restrict__ Wm,
                float* __restrict__ out,
                const int* __restrict__ flags)
{
    __shared__ double yd[H];
    __shared__ double parts[4 * E];
    __shared__ double ss[256];

    const int t = threadIdx.x;
    const int count = flags[0];

    for (int j = blockIdx.x; j < count; j += gridDim.x) {
        const int r = flags[1 + j];
        const float* xr = x + (size_t)r * H;

        double s = 0.0;
#pragma unroll
        for (int i = 0; i < 8; ++i) {
            const int h = t * 8 + i;
            const double xv = (double)xr[h];
            s += xv * xv;
            yd[h] = xv * (double)pds[h];
        }
        ss[t] = s;
        __syncthreads();

        const int ex = t & 63;
        const int sl = t >> 6;
        const float* wp = Wm + (size_t)(sl * 512) * E + ex;
        double acc = 0.0;
#pragma unroll 8
        for (int h = 0; h < 512; ++h)
            acc = fma(yd[sl * 512 + h], (double)wp[(size_t)h * E], acc);
        parts[sl * E + ex] = acc;
        __syncthreads();

        if (t < 64) {
            const int lane = t;
            double tot = ss[lane * 4] + ss[lane * 4 + 1] + ss[lane * 4 + 2] + ss[lane * 4 + 3];
#pragma unroll
            for (int off = 32; off >= 1; off >>= 1)
                tot += __shfl_xor(tot, off);
            const double sf = (1.0 / sqrt(tot * (1.0 / (double)H) + 1e-6)) * 0.022097086912079608;

            const double Ld = parts[0 * E + lane] + parts[1 * E + lane]
                            + parts[2 * E + lane] + parts[3 * E + lane];
            const float L = (float)(Ld * sf);

            float m = L;
#pragma unroll
            for (int off = 32; off >= 1; off >>= 1)
                m = fmaxf(m, __shfl_xor(m, off));
            const float ev = (float)exp((double)(L - m));
            float S = ev;
#pragma unroll
            for (int off = 32; off >= 1; off >>= 1)
                S += __shfl_xor(S, off);
            const float p = ev / S;

            float v1 = p; int i1 = lane;
#pragma unroll
            for (int off = 32; off >= 1; off >>= 1) {
                const float ov = __shfl_xor(v1, off);
                const int   oi = __shfl_xor(i1, off);
                if (ov > v1 || (ov == v1 && oi < i1)) { v1 = ov; i1 = oi; }
            }
            float v2 = (lane == i1) ? -1.0f : p; int i2 = lane;
#pragma unroll
            for (int off = 32; off >= 1; off >>= 1) {
                const float ov = __shfl_xor(v2, off);
                const int   oi = __shfl_xor(i2, off);
                if (ov > v2 || (ov == v2 && oi < i2)) { v2 = ov; i2 = oi; }
            }

            const float denom = fmaxf(v1 + v2, 1e-9f);
            const float wA = v1 / denom;
            const float wB = v2 / denom;
            const float o  = (lane == i1) ? wA : ((lane == i2) ? wB : 0.0f);
            out[(size_t)r * E + lane] = o;
        }
        __syncthreads();
    }
}

// ============ round-5 fallback (verified) in case ws_size is small ============
__global__ void zero_cnt(int* __restrict__ flags) {
    if (threadIdx.x == 0 && blockIdx.x == 0) flags[0] = 0;
}

__global__ __launch_bounds__(256)
void router_f32(const float* __restrict__ x,
                const float* __restrict__ pds,
                const float* __restrict__ Wm,
                float* __restrict__ out,
                int* __restrict__ flags)
{
    __shared__ __align__(16) float yb[RB * PITCH];
    __shared__ float ssbuf[256];
    __shared__ float sfac[RB];

    const int t    = threadIdx.x;
    const int wv_i = t >> 6;
    const int lane = t & 63;
    const int g    = lane >> 4;
    const int e0   = (lane & 15) << 2;

    const int row0 = blockIdx.x * RB;
    const int srow = t >> 4;
    const int sseg = t & 15;

    const float* xrow = x + (size_t)(row0 + srow) * H;

    float acc[4][4];
#pragma unroll
    for (int a = 0; a < 4; ++a)
#pragma unroll
        for (int b = 0; b < 4; ++b) acc[a][b] = 0.0f;

    float sumsq = 0.0f;
    float4 xv[8];
#pragma unroll
    for (int i = 0; i < 8; ++i)
        xv[i] = *(const float4*)(xrow + sseg * 4 + i * 64);

    for (int c = 0; c < NCH; ++c) {
        const float* pbase = pds + c * CB;
#pragma unroll
        for (int i = 0; i < 8; ++i) {
            const int hl = sseg * 4 + i * 64;
            const float4 a4 = xv[i];
            const float4 p4 = *(const float4*)(pbase + hl);
            sumsq += a4.x * a4.x + a4.y * a4.y + a4.z * a4.z + a4.w * a4.w;
            float4 y4;
            y4.x = a4.x * p4.x; y4.y = a4.y * p4.y;
            y4.z = a4.z * p4.z; y4.w = a4.w * p4.w;
            *(float4*)(&yb[srow * PITCH + hl]) = y4;
        }
        __syncthreads();

        if (c + 1 < NCH) {
            const int h0n = (c + 1) * CB;
#pragma unroll
            for (int i = 0; i < 8; ++i)
                xv[i] = *(const float4*)(xrow + h0n + sseg * 4 + i * 64);
        }

        const int hb = wv_i * 128;
        const float* wbase = Wm + (size_t)(c * CB) * E + e0;
#pragma unroll 2
        for (int s = 0; s < 32; ++s) {
            const int hh = hb + s * 4;
            const float4 w0 = *(const float4*)(wbase + (size_t)(hh + 0) * E);
            const float4 w1 = *(const float4*)(wbase + (size_t)(hh + 1) * E);
            const float4 w2 = *(const float4*)(wbase + (size_t)(hh + 2) * E);
            const float4 w3 = *(const float4*)(wbase + (size_t)(hh + 3) * E);
#pragma unroll
            for (int rr = 0; rr < 4; ++rr) {
                const float4 y4 = *(const float4*)(&yb[(4 * rr + g) * PITCH + hh]);
                acc[rr][0] = fmaf(y4.w, w3.x, fmaf(y4.z, w2.x, fmaf(y4.y, w1.x, fmaf(y4.x, w0.x, acc[rr][0]))));
                acc[rr][1] = fmaf(y4.w, w3.y, fmaf(y4.z, w2.y, fmaf(y4.y, w1.y, fmaf(y4.x, w0.y, acc[rr][1]))));
                acc[rr][2] = fmaf(y4.w, w3.z, fmaf(y4.z, w2.z, fmaf(y4.y, w1.z, fmaf(y4.x, w0.z, acc[rr][2]))));
                acc[rr][3] = fmaf(y4.w, w3.w, fmaf(y4.z, w2.w, fmaf(y4.y, w1.w, fmaf(y4.x, w0.w, acc[rr][3]))));
            }
        }
        __syncthreads();
    }

    ssbuf[t] = sumsq;
    __syncthreads();
    if (t < RB) {
        float tot = 0.0f;
#pragma unroll
        for (int i = 0; i < 16; ++i) tot += ssbuf[t * 16 + i];
        sfac[t] = rsqrtf(tot * (1.0f / (float)H) + 1e-6f) * 0.022097086912079608f;
    }

#pragma unroll
    for (int rr = 0; rr < 4; ++rr) {
        const int r = 4 * rr + g;
        *(float4*)(&yb[((wv_i * RB) + r) * E + e0]) =
            make_float4(acc[rr][0], acc[rr][1], acc[rr][2], acc[rr][3]);
    }
    __syncthreads();

#pragma unroll
    for (int rr = 0; rr < 4; ++rr) {
        const int r = wv_i * 4 + rr;
        float L = yb[(0 * RB + r) * E + lane] + yb[(1 * RB + r) * E + lane]
                + yb[(2 * RB + r) * E + lane] + yb[(3 * RB + r) * E + lane];
        L *= sfac[r];

        float m = L;
#pragma unroll
        for (int off = 32; off >= 1; off >>= 1)
            m = fmaxf(m, __shfl_xor(m, off));
        const float ev = expf(L - m);
        float S = ev;
#pragma unroll
        for (int off = 32; off >= 1; off >>= 1)
            S += __shfl_xor(S, off);
        const float p = ev / S;

        float v1 = p; int i1 = lane;
#pragma unroll
        for (int off = 32; off >= 1; off >>= 1) {
            const float ov = __shfl_xor(v1, off);
            const int   oi = __shfl_xor(i1, off);
            if (ov > v1 || (ov == v1 && oi < i1)) { v1 = ov; i1 = oi; }
        }
        float v2 = (lane == i1) ? -1.0f : p; int i2 = lane;
#pragma unroll
        for (int off = 32; off >= 1; off >>= 1) {
            const float ov = __shfl_xor(v2, off);
            const int   oi = __shfl_xor(i2, off);
            if (ov > v2 || (ov == v2 && oi < i2)) { v2 = ov; i2 = oi; }
        }
        float v3 = (lane == i1 || lane == i2) ? -1.0f : p;
#pragma unroll
        for (int off = 32; off >= 1; off >>= 1)
            v3 = fmaxf(v3, __shfl_xor(v3, off));

        if (lane == 0 && (v2 - v3) < TAU) {
            const int k = atomicAdd(flags, 1);
            flags[1 + k] = row0 + r;
        }

        const float denom = fmaxf(v1 + v2, 1e-9f);
        const float wA = v1 / denom;
        const float wB = v2 / denom;
        const float o  = (lane == i1) ? wA : ((lane == i2) ? wB : 0.0f);
        out[(size_t)(row0 + r) * E + lane] = o;
    }
}

extern "C" void kernel_launch(void* const* d_in, const int* in_sizes, int n_in,
                              void* d_out, int out_size, void* d_ws, size_t ws_size,
                              hipStream_t stream) {
    const float* x   = (const float*)d_in[0];
    const float* pds = (const float*)d_in[1];
    const float* Wm  = (const float*)d_in[2];
    float* out = (float*)d_out;
    int* flags = (int*)d_ws;

    const int T = in_sizes[0] / H;   // 16384

    if (ws_size >= WS_NEEDED) {
        unsigned short* whi = (unsigned short*)((char*)d_ws + WHI_OFF);
        unsigned short* wlo = (unsigned short*)((char*)d_ws + WLO_OFF);
        hipLaunchKernelGGL(prep_w,     dim3(256),    dim3(64),  0, stream, Wm, pds, flags, whi, wlo);
        hipLaunchKernelGGL(router_4t,  dim3(T / MT), dim3(512), 0, stream, x, whi, wlo, out, flags);
        hipLaunchKernelGGL(router_fix, dim3(128),    dim3(256), 0, stream, x, pds, Wm, out, flags);
    } else {
        hipLaunchKernelGGL(zero_cnt,   dim3(1),      dim3(64),  0, stream, flags);
        hipLaunchKernelGGL(router_f32, dim3(T / RB), dim3(256), 0, stream, x, pds, Wm, out, flags);
        hipLaunchKernelGGL(router_fix, dim3(128),    dim3(256), 0, stream, x, pds, Wm, out, flags);
    }
}